// Round 1
// baseline (4369.816 us; speedup 1.0000x reference)
//
#include <hip/hip_runtime.h>
#include <hip/hip_bf16.h>
#include <cstdint>
#include <cstddef>

#define D_IN  128
#define D_H   256
#define D_OUT 64

// ---------------- init: zero counters ----------------
__global__ void init_k(int* cnt, int* cursor, int* gmax, int n) {
  int i = blockIdx.x * blockDim.x + threadIdx.x;
  int stride = gridDim.x * blockDim.x;
  for (; i < 2 * n + 1; i += stride) {
    if (i < n) cnt[i] = 0;
    else if (i < 2 * n) cursor[i - n] = 0;
    else gmax[0] = 0;
  }
}

// ---------------- extract edges (handles int32 or int64 storage) ----------------
__global__ void edges_k(const int* __restrict__ raw, int* __restrict__ src,
                        int* __restrict__ dst, int E) {
  __shared__ int flag;
  if (threadIdx.x == 0) {
    int zeros = 0;
    for (int i = 0; i < 64; ++i) zeros += (raw[2 * i + 1] == 0) ? 1 : 0;
    flag = (zeros >= 60) ? 1 : 0;  // int64: odd words are high halves == 0
  }
  __syncthreads();
  int is64 = flag;
  int idx = blockIdx.x * blockDim.x + threadIdx.x;
  int stride = gridDim.x * blockDim.x;
  for (; idx < E; idx += stride) {
    if (is64) {
      src[idx] = raw[2 * idx];
      dst[idx] = raw[2 * (E + idx)];
    } else {
      src[idx] = raw[idx];
      dst[idx] = raw[E + idx];
    }
  }
}

// ---------------- degree count ----------------
__global__ void count_k(const int* __restrict__ dst, int* cnt, int E) {
  int idx = blockIdx.x * blockDim.x + threadIdx.x;
  int stride = gridDim.x * blockDim.x;
  for (; idx < E; idx += stride) atomicAdd(&cnt[dst[idx]], 1);
}

// ---------------- dinv = rsqrt(deg+1) ----------------
__global__ void deg_k(const int* __restrict__ cnt, float* __restrict__ dinv, int n) {
  int i = blockIdx.x * blockDim.x + threadIdx.x;
  if (i < n) dinv[i] = rsqrtf((float)cnt[i] + 1.0f);
}

// ---------------- exclusive scan of cnt -> offsets (single block, n <= 10240) ----------------
__global__ void scan_k(const int* __restrict__ cnt, int* __restrict__ offs, int n) {
  __shared__ int sums[1024];
  int t = threadIdx.x;
  const int CH = 10;
  int base = t * CH;
  int local[CH];
  int s = 0;
  for (int i = 0; i < CH; ++i) {
    int v = (base + i < n) ? cnt[base + i] : 0;
    local[i] = s;
    s += v;
  }
  sums[t] = s;
  __syncthreads();
  for (int off = 1; off < 1024; off <<= 1) {
    int v = (t >= off) ? sums[t - off] : 0;
    __syncthreads();
    sums[t] += v;
    __syncthreads();
  }
  int prefix = (t > 0) ? sums[t - 1] : 0;
  for (int i = 0; i < CH; ++i)
    if (base + i < n) offs[base + i] = prefix + local[i];
  if (t == 1023) offs[n] = sums[1023];
}

// ---------------- fill CSR ----------------
__global__ void fill_k(const int* __restrict__ src, const int* __restrict__ dst,
                       const int* __restrict__ offs, int* __restrict__ cursor,
                       const float* __restrict__ dinv, int* __restrict__ csr_src,
                       float* __restrict__ csr_norm, int E) {
  int idx = blockIdx.x * blockDim.x + threadIdx.x;
  int stride = gridDim.x * blockDim.x;
  for (; idx < E; idx += stride) {
    int d = dst[idx], s = src[idx];
    int pos = atomicAdd(&cursor[d], 1);
    int slot = offs[d] + pos;
    csr_src[slot] = s;
    csr_norm[slot] = dinv[s] * dinv[d];
  }
}

// ---------------- generic fp32 tiled GEMM: C[M,N] = A[M,K] @ B[K,N] ----------------
// BM=BN=64, BK=16, 256 threads, 4x4 micro-tile. K % 16 == 0, N % 64 == 0.
__global__ void gemm_k(const float* __restrict__ A, const float* __restrict__ B,
                       float* __restrict__ C, int M, int N, int K) {
  __shared__ float As[16][64];
  __shared__ float Bs[16][64];
  int t = threadIdx.x;
  int bm = blockIdx.x * 64, bn = blockIdx.y * 64;
  int tx = t & 15, ty = t >> 4;
  int lr = t >> 2;            // A-load row 0..63
  int lk = (t & 3) * 4;       // A-load k offset
  int br = t >> 4;            // B-load k row 0..15
  int bc = (t & 15) * 4;      // B-load col offset
  float acc[4][4] = {};
  for (int k0 = 0; k0 < K; k0 += 16) {
    float4 av = make_float4(0.f, 0.f, 0.f, 0.f);
    if (bm + lr < M) av = *(const float4*)&A[(size_t)(bm + lr) * K + k0 + lk];
    As[lk + 0][lr] = av.x;
    As[lk + 1][lr] = av.y;
    As[lk + 2][lr] = av.z;
    As[lk + 3][lr] = av.w;
    float4 bv = *(const float4*)&B[(size_t)(k0 + br) * N + bn + bc];
    *(float4*)&Bs[br][bc] = bv;
    __syncthreads();
#pragma unroll
    for (int k = 0; k < 16; ++k) {
      float4 a = *(const float4*)&As[k][ty * 4];
      float4 b = *(const float4*)&Bs[k][tx * 4];
      acc[0][0] += a.x * b.x; acc[0][1] += a.x * b.y; acc[0][2] += a.x * b.z; acc[0][3] += a.x * b.w;
      acc[1][0] += a.y * b.x; acc[1][1] += a.y * b.y; acc[1][2] += a.y * b.z; acc[1][3] += a.y * b.w;
      acc[2][0] += a.z * b.x; acc[2][1] += a.z * b.y; acc[2][2] += a.z * b.z; acc[2][3] += a.z * b.w;
      acc[3][0] += a.w * b.x; acc[3][1] += a.w * b.y; acc[3][2] += a.w * b.z; acc[3][3] += a.w * b.w;
    }
    __syncthreads();
  }
  for (int r = 0; r < 4; ++r) {
    int row = bm + ty * 4 + r;
    if (row < M)
      *(float4*)&C[(size_t)row * N + bn + tx * 4] =
          make_float4(acc[r][0], acc[r][1], acc[r][2], acc[r][3]);
  }
}

// ---------------- GCN aggregation layer 1 (D_H=256), wave per node ----------------
__global__ void agg1_k(const float* __restrict__ h, const int* __restrict__ offs,
                       const int* __restrict__ csr_src, const float* __restrict__ csr_norm,
                       const float* __restrict__ dinv, const float* __restrict__ b1,
                       float* __restrict__ h1, int n) {
  int wid = blockIdx.x * 4 + (threadIdx.x >> 6);
  int lane = threadIdx.x & 63;
  if (wid >= n) return;
  float di = dinv[wid];
  float selfw = di * di;
  float4 acc = *(const float4*)&b1[lane * 4];
  float4 hv = *(const float4*)&h[(size_t)wid * D_H + lane * 4];
  acc.x += hv.x * selfw; acc.y += hv.y * selfw; acc.z += hv.z * selfw; acc.w += hv.w * selfw;
  int e0 = offs[wid], e1 = offs[wid + 1];
  for (int e = e0; e < e1; ++e) {
    int s = csr_src[e];
    float w = csr_norm[e];
    float4 v = *(const float4*)&h[(size_t)s * D_H + lane * 4];
    acc.x += v.x * w; acc.y += v.y * w; acc.z += v.z * w; acc.w += v.w * w;
  }
  acc.x = fmaxf(acc.x, 0.f); acc.y = fmaxf(acc.y, 0.f);
  acc.z = fmaxf(acc.z, 0.f); acc.w = fmaxf(acc.w, 0.f);
  *(float4*)&h1[(size_t)wid * D_H + lane * 4] = acc;
}

// ---------------- GCN aggregation layer 2 (D_OUT=64) + row sq, wave per node ----------------
__global__ void agg2_k(const float* __restrict__ h2, const int* __restrict__ offs,
                       const int* __restrict__ csr_src, const float* __restrict__ csr_norm,
                       const float* __restrict__ dinv, const float* __restrict__ b2,
                       float* __restrict__ z, float* __restrict__ sq, int n) {
  int wid = blockIdx.x * 4 + (threadIdx.x >> 6);
  int lane = threadIdx.x & 63;
  if (wid >= n) return;
  float di = dinv[wid];
  float selfw = di * di;
  float acc = b2[lane] + h2[(size_t)wid * D_OUT + lane] * selfw;
  int e0 = offs[wid], e1 = offs[wid + 1];
  for (int e = e0; e < e1; ++e) {
    int s = csr_src[e];
    float w = csr_norm[e];
    acc += h2[(size_t)s * D_OUT + lane] * w;
  }
  z[(size_t)wid * D_OUT + lane] = acc;
  float ss = acc * acc;
#pragma unroll
  for (int o = 32; o > 0; o >>= 1) ss += __shfl_xor(ss, o, 64);
  if (lane == 0) sq[wid] = ss;
}

// ---------------- decode pass 1: dist = sqrt(max(sq_i+sq_j-2*z_i.z_j,0)), store + global max ----------------
// 128x128 tile, K=64 resident in LDS (XOR-swizzled float4 slots), 8x8 micro-tile.
__global__ __launch_bounds__(256, 2) void decode_k(const float* __restrict__ Z,
                                                   const float* __restrict__ sq,
                                                   float* __restrict__ dist,
                                                   int* __restrict__ gmax, int n) {
  __shared__ float Zi[128][64];
  __shared__ float Zj[128][64];
  int t = threadIdx.x;
  int i0 = blockIdx.y * 128, j0 = blockIdx.x * 128;
#pragma unroll
  for (int it = 0; it < 8; ++it) {
    int idx = t + it * 256;
    int row = idx >> 4, slot = idx & 15;
    int sw = (slot ^ (row >> 3)) & 15;
    float4 v = make_float4(0.f, 0.f, 0.f, 0.f);
    if (i0 + row < n) v = *(const float4*)&Z[(size_t)(i0 + row) * D_OUT + slot * 4];
    *(float4*)&Zi[row][sw * 4] = v;
    float4 w = make_float4(0.f, 0.f, 0.f, 0.f);
    if (j0 + row < n) w = *(const float4*)&Z[(size_t)(j0 + row) * D_OUT + slot * 4];
    *(float4*)&Zj[row][sw * 4] = w;
  }
  __syncthreads();
  int tx = t & 15, ty = t >> 4;
  int r0 = ty * 8, c0 = tx * 8;
  float acc[8][8] = {};
#pragma unroll
  for (int ks = 0; ks < 16; ++ks) {
    float4 a[8], b[8];
#pragma unroll
    for (int r = 0; r < 8; ++r)
      a[r] = *(const float4*)&Zi[r0 + r][((ks ^ ((r0 + r) >> 3)) & 15) * 4];
#pragma unroll
    for (int c = 0; c < 8; ++c)
      b[c] = *(const float4*)&Zj[c0 + c][((ks ^ ((c0 + c) >> 3)) & 15) * 4];
#pragma unroll
    for (int r = 0; r < 8; ++r)
#pragma unroll
      for (int c = 0; c < 8; ++c)
        acc[r][c] += a[r].x * b[c].x + a[r].y * b[c].y + a[r].z * b[c].z + a[r].w * b[c].w;
  }
  float sqa[8], sqb[8];
#pragma unroll
  for (int r = 0; r < 8; ++r) { int i = i0 + r0 + r; sqa[r] = (i < n) ? sq[i] : 0.f; }
#pragma unroll
  for (int c = 0; c < 8; ++c) { int j = j0 + c0 + c; sqb[c] = (j < n) ? sq[j] : 0.f; }
  float lmax = 0.f;
  bool interior = (i0 + 128 <= n) && (j0 + 128 <= n);
  if (interior) {
#pragma unroll
    for (int r = 0; r < 8; ++r) {
      size_t base = (size_t)(i0 + r0 + r) * n + (j0 + c0);
      float rowv[8];
#pragma unroll
      for (int c = 0; c < 8; ++c) {
        float d2 = sqa[r] + sqb[c] - 2.f * acc[r][c];
        float dd = (d2 > 0.f) ? sqrtf(d2) : 0.f;
        rowv[c] = dd;
        lmax = fmaxf(lmax, dd);
      }
      *(float4*)&dist[base]     = make_float4(rowv[0], rowv[1], rowv[2], rowv[3]);
      *(float4*)&dist[base + 4] = make_float4(rowv[4], rowv[5], rowv[6], rowv[7]);
    }
  } else {
    for (int r = 0; r < 8; ++r) {
      int i = i0 + r0 + r;
      if (i >= n) continue;
      for (int c = 0; c < 8; ++c) {
        int j = j0 + c0 + c;
        if (j >= n) continue;
        float d2 = sqa[r] + sqb[c] - 2.f * acc[r][c];
        float dd = (d2 > 0.f) ? sqrtf(d2) : 0.f;
        dist[(size_t)i * n + j] = dd;
        lmax = fmaxf(lmax, dd);
      }
    }
  }
#pragma unroll
  for (int o = 32; o > 0; o >>= 1) lmax = fmaxf(lmax, __shfl_xor(lmax, o, 64));
  if ((t & 63) == 0) atomicMax(gmax, __float_as_int(lmax));
}

// ---------------- decode pass 2: out = 1 - dist/m ----------------
__global__ void final_k(float* __restrict__ out, const int* __restrict__ gmax, size_t n2) {
  float m = __int_as_float(*gmax);
  float s = (m > 0.f) ? (1.f / m) : 0.f;
  size_t idx = (size_t)blockIdx.x * blockDim.x + threadIdx.x;
  size_t stride = (size_t)gridDim.x * blockDim.x;
  size_t n4 = n2 / 4;
  float4* o = (float4*)out;
  for (; idx < n4; idx += stride) {
    float4 v = o[idx];
    v.x = 1.f - v.x * s;
    v.y = 1.f - v.y * s;
    v.z = 1.f - v.z * s;
    v.w = 1.f - v.w * s;
    o[idx] = v;
  }
}

extern "C" void kernel_launch(void* const* d_in, const int* in_sizes, int n_in,
                              void* d_out, int out_size, void* d_ws, size_t ws_size,
                              hipStream_t stream) {
  const float* x  = (const float*)d_in[0];
  const int* eraw = (const int*)d_in[1];
  const float* W1 = (const float*)d_in[2];
  const float* b1 = (const float*)d_in[3];
  const float* W2 = (const float*)d_in[4];
  const float* b2 = (const float*)d_in[5];
  float* out = (float*)d_out;

  const int n = in_sizes[0] / D_IN;   // 10000
  const int E = in_sizes[1] / 2;      // 320000

  // workspace carve (256B aligned)
  char* p = (char*)d_ws;
  auto alloc = [&](size_t bytes) {
    void* r = (void*)p;
    p += (bytes + 255) & ~(size_t)255;
    return r;
  };
  int*   cnt      = (int*)alloc((size_t)n * 4);
  int*   offs     = (int*)alloc((size_t)(n + 1) * 4);
  int*   cursor   = (int*)alloc((size_t)n * 4);
  int*   esrc     = (int*)alloc((size_t)E * 4);
  int*   edst     = (int*)alloc((size_t)E * 4);
  int*   csr_src  = (int*)alloc((size_t)E * 4);
  float* csr_norm = (float*)alloc((size_t)E * 4);
  float* dinv     = (float*)alloc((size_t)n * 4);
  float* h        = (float*)alloc((size_t)n * D_H * 4);
  float* h1       = (float*)alloc((size_t)n * D_H * 4);
  float* h2      = (float*)alloc((size_t)n * D_OUT * 4);
  float* z        = (float*)alloc((size_t)n * D_OUT * 4);
  float* sq       = (float*)alloc((size_t)n * 4);
  int*   gmax     = (int*)alloc(4);

  init_k<<<64, 256, 0, stream>>>(cnt, cursor, gmax, n);
  edges_k<<<512, 256, 0, stream>>>(eraw, esrc, edst, E);
  count_k<<<512, 256, 0, stream>>>(edst, cnt, E);
  deg_k<<<(n + 255) / 256, 256, 0, stream>>>(cnt, dinv, n);
  scan_k<<<1, 1024, 0, stream>>>(cnt, offs, n);
  fill_k<<<512, 256, 0, stream>>>(esrc, edst, offs, cursor, dinv, csr_src, csr_norm, E);

  // layer 1
  gemm_k<<<dim3((n + 63) / 64, D_H / 64), 256, 0, stream>>>(x, W1, h, n, D_H, D_IN);
  agg1_k<<<(n + 3) / 4, 256, 0, stream>>>(h, offs, csr_src, csr_norm, dinv, b1, h1, n);

  // layer 2
  gemm_k<<<dim3((n + 63) / 64, D_OUT / 64), 256, 0, stream>>>(h1, W2, h2, n, D_OUT, D_H);
  agg2_k<<<(n + 3) / 4, 256, 0, stream>>>(h2, offs, csr_src, csr_norm, dinv, b2, z, sq, n);

  // decode
  int gt = (n + 127) / 128;
  decode_k<<<dim3(gt, gt), 256, 0, stream>>>(z, sq, out, gmax, n);
  final_k<<<2048, 256, 0, stream>>>(out, gmax, (size_t)n * n);
}

// Round 2
// 2011.400 us; speedup vs baseline: 2.1725x; 2.1725x over previous
//
#include <hip/hip_runtime.h>
#include <hip/hip_bf16.h>
#include <cstdint>
#include <cstddef>

#define D_IN  128
#define D_H   256
#define D_OUT 64

// ---------------- init: zero counters ----------------
__global__ void init_k(int* cnt, int* cursor, int* gmax, int n) {
  int i = blockIdx.x * blockDim.x + threadIdx.x;
  int stride = gridDim.x * blockDim.x;
  for (; i < 2 * n + 1; i += stride) {
    if (i < n) cnt[i] = 0;
    else if (i < 2 * n) cursor[i - n] = 0;
    else gmax[0] = 0;
  }
}

// ---------------- extract edges (handles int32 or int64 storage) ----------------
__global__ void edges_k(const int* __restrict__ raw, int* __restrict__ src,
                        int* __restrict__ dst, int E) {
  __shared__ int flag;
  if (threadIdx.x == 0) {
    int zeros = 0;
    for (int i = 0; i < 64; ++i) zeros += (raw[2 * i + 1] == 0) ? 1 : 0;
    flag = (zeros >= 60) ? 1 : 0;  // int64: odd words are high halves == 0
  }
  __syncthreads();
  int is64 = flag;
  int idx = blockIdx.x * blockDim.x + threadIdx.x;
  int stride = gridDim.x * blockDim.x;
  for (; idx < E; idx += stride) {
    if (is64) {
      src[idx] = raw[2 * idx];
      dst[idx] = raw[2 * (E + idx)];
    } else {
      src[idx] = raw[idx];
      dst[idx] = raw[E + idx];
    }
  }
}

// ---------------- degree count ----------------
__global__ void count_k(const int* __restrict__ dst, int* cnt, int E) {
  int idx = blockIdx.x * blockDim.x + threadIdx.x;
  int stride = gridDim.x * blockDim.x;
  for (; idx < E; idx += stride) atomicAdd(&cnt[dst[idx]], 1);
}

// ---------------- dinv = rsqrt(deg+1) ----------------
__global__ void deg_k(const int* __restrict__ cnt, float* __restrict__ dinv, int n) {
  int i = blockIdx.x * blockDim.x + threadIdx.x;
  if (i < n) dinv[i] = rsqrtf((float)cnt[i] + 1.0f);
}

// ---------------- exclusive scan of cnt -> offsets (single block, n <= 10240) ----------------
__global__ void scan_k(const int* __restrict__ cnt, int* __restrict__ offs, int n) {
  __shared__ int sums[1024];
  int t = threadIdx.x;
  const int CH = 10;
  int base = t * CH;
  int local[CH];
  int s = 0;
  for (int i = 0; i < CH; ++i) {
    int v = (base + i < n) ? cnt[base + i] : 0;
    local[i] = s;
    s += v;
  }
  sums[t] = s;
  __syncthreads();
  for (int off = 1; off < 1024; off <<= 1) {
    int v = (t >= off) ? sums[t - off] : 0;
    __syncthreads();
    sums[t] += v;
    __syncthreads();
  }
  int prefix = (t > 0) ? sums[t - 1] : 0;
  for (int i = 0; i < CH; ++i)
    if (base + i < n) offs[base + i] = prefix + local[i];
  if (t == 1023) offs[n] = sums[1023];
}

// ---------------- fill CSR ----------------
__global__ void fill_k(const int* __restrict__ src, const int* __restrict__ dst,
                       const int* __restrict__ offs, int* __restrict__ cursor,
                       const float* __restrict__ dinv, int* __restrict__ csr_src,
                       float* __restrict__ csr_norm, int E) {
  int idx = blockIdx.x * blockDim.x + threadIdx.x;
  int stride = gridDim.x * blockDim.x;
  for (; idx < E; idx += stride) {
    int d = dst[idx], s = src[idx];
    int pos = atomicAdd(&cursor[d], 1);
    int slot = offs[d] + pos;
    csr_src[slot] = s;
    csr_norm[slot] = dinv[s] * dinv[d];
  }
}

// ---------------- generic fp32 tiled GEMM: C[M,N] = A[M,K] @ B[K,N] ----------------
// BM=BN=64, BK=16, 256 threads, 4x4 micro-tile. K % 16 == 0, N % 64 == 0.
__global__ void gemm_k(const float* __restrict__ A, const float* __restrict__ B,
                       float* __restrict__ C, int M, int N, int K) {
  __shared__ float As[16][64];
  __shared__ float Bs[16][64];
  int t = threadIdx.x;
  int bm = blockIdx.x * 64, bn = blockIdx.y * 64;
  int tx = t & 15, ty = t >> 4;
  int lr = t >> 2;            // A-load row 0..63
  int lk = (t & 3) * 4;       // A-load k offset
  int br = t >> 4;            // B-load k row 0..15
  int bc = (t & 15) * 4;      // B-load col offset
  float acc[4][4] = {};
  for (int k0 = 0; k0 < K; k0 += 16) {
    float4 av = make_float4(0.f, 0.f, 0.f, 0.f);
    if (bm + lr < M) av = *(const float4*)&A[(size_t)(bm + lr) * K + k0 + lk];
    As[lk + 0][lr] = av.x;
    As[lk + 1][lr] = av.y;
    As[lk + 2][lr] = av.z;
    As[lk + 3][lr] = av.w;
    float4 bv = *(const float4*)&B[(size_t)(k0 + br) * N + bn + bc];
    *(float4*)&Bs[br][bc] = bv;
    __syncthreads();
#pragma unroll
    for (int k = 0; k < 16; ++k) {
      float4 a = *(const float4*)&As[k][ty * 4];
      float4 b = *(const float4*)&Bs[k][tx * 4];
      acc[0][0] += a.x * b.x; acc[0][1] += a.x * b.y; acc[0][2] += a.x * b.z; acc[0][3] += a.x * b.w;
      acc[1][0] += a.y * b.x; acc[1][1] += a.y * b.y; acc[1][2] += a.y * b.z; acc[1][3] += a.y * b.w;
      acc[2][0] += a.z * b.x; acc[2][1] += a.z * b.y; acc[2][2] += a.z * b.z; acc[2][3] += a.z * b.w;
      acc[3][0] += a.w * b.x; acc[3][1] += a.w * b.y; acc[3][2] += a.w * b.z; acc[3][3] += a.w * b.w;
    }
    __syncthreads();
  }
  for (int r = 0; r < 4; ++r) {
    int row = bm + ty * 4 + r;
    if (row < M)
      *(float4*)&C[(size_t)row * N + bn + tx * 4] =
          make_float4(acc[r][0], acc[r][1], acc[r][2], acc[r][3]);
  }
}

// ---------------- GCN aggregation layer 1 (D_H=256), wave per node ----------------
__global__ void agg1_k(const float* __restrict__ h, const int* __restrict__ offs,
                       const int* __restrict__ csr_src, const float* __restrict__ csr_norm,
                       const float* __restrict__ dinv, const float* __restrict__ b1,
                       float* __restrict__ h1, int n) {
  int wid = blockIdx.x * 4 + (threadIdx.x >> 6);
  int lane = threadIdx.x & 63;
  if (wid >= n) return;
  float di = dinv[wid];
  float selfw = di * di;
  float4 acc = *(const float4*)&b1[lane * 4];
  float4 hv = *(const float4*)&h[(size_t)wid * D_H + lane * 4];
  acc.x += hv.x * selfw; acc.y += hv.y * selfw; acc.z += hv.z * selfw; acc.w += hv.w * selfw;
  int e0 = offs[wid], e1 = offs[wid + 1];
  for (int e = e0; e < e1; ++e) {
    int s = csr_src[e];
    float w = csr_norm[e];
    float4 v = *(const float4*)&h[(size_t)s * D_H + lane * 4];
    acc.x += v.x * w; acc.y += v.y * w; acc.z += v.z * w; acc.w += v.w * w;
  }
  acc.x = fmaxf(acc.x, 0.f); acc.y = fmaxf(acc.y, 0.f);
  acc.z = fmaxf(acc.z, 0.f); acc.w = fmaxf(acc.w, 0.f);
  *(float4*)&h1[(size_t)wid * D_H + lane * 4] = acc;
}

// ---------------- GCN aggregation layer 2 (D_OUT=64) + row sq, wave per node ----------------
__global__ void agg2_k(const float* __restrict__ h2, const int* __restrict__ offs,
                       const int* __restrict__ csr_src, const float* __restrict__ csr_norm,
                       const float* __restrict__ dinv, const float* __restrict__ b2,
                       float* __restrict__ z, float* __restrict__ sq, int n) {
  int wid = blockIdx.x * 4 + (threadIdx.x >> 6);
  int lane = threadIdx.x & 63;
  if (wid >= n) return;
  float di = dinv[wid];
  float selfw = di * di;
  float acc = b2[lane] + h2[(size_t)wid * D_OUT + lane] * selfw;
  int e0 = offs[wid], e1 = offs[wid + 1];
  for (int e = e0; e < e1; ++e) {
    int s = csr_src[e];
    float w = csr_norm[e];
    acc += h2[(size_t)s * D_OUT + lane] * w;
  }
  z[(size_t)wid * D_OUT + lane] = acc;
  float ss = acc * acc;
#pragma unroll
  for (int o = 32; o > 0; o >>= 1) ss += __shfl_xor(ss, o, 64);
  if (lane == 0) sq[wid] = ss;
}

// ---------------- decode pass 1: dist = sqrt(max(sq_i+sq_j-2*z_i.z_j,0)), store + global max ----------------
// 128x128 tile, K=64 resident in LDS (XOR-swizzled float4 slots), 8x8 micro-tile.
// __launch_bounds__(256,1): live set ~110 VGPRs (64 acc + 32 b + 4 a + addr);
// the earlier (256,2) build capped VGPR=128 and spilled acc through the ks
// loop -> 8.3 GB scratch writes, 4 ms. Do NOT constrain the allocator here.
__global__ __launch_bounds__(256, 1) void decode_k(const float* __restrict__ Z,
                                                   const float* __restrict__ sq,
                                                   float* __restrict__ dist,
                                                   int* __restrict__ gmax, int n) {
  __shared__ float Zi[128][64];
  __shared__ float Zj[128][64];
  int t = threadIdx.x;
  int i0 = blockIdx.y * 128, j0 = blockIdx.x * 128;
#pragma unroll
  for (int it = 0; it < 8; ++it) {
    int idx = t + it * 256;
    int row = idx >> 4, slot = idx & 15;
    int sw = (slot ^ (row >> 3)) & 15;
    float4 v = make_float4(0.f, 0.f, 0.f, 0.f);
    if (i0 + row < n) v = *(const float4*)&Z[(size_t)(i0 + row) * D_OUT + slot * 4];
    *(float4*)&Zi[row][sw * 4] = v;
    float4 w = make_float4(0.f, 0.f, 0.f, 0.f);
    if (j0 + row < n) w = *(const float4*)&Z[(size_t)(j0 + row) * D_OUT + slot * 4];
    *(float4*)&Zj[row][sw * 4] = w;
  }
  __syncthreads();
  int tx = t & 15, ty = t >> 4;
  int r0 = ty * 8, c0 = tx * 8;
  // note: (r0+r)>>3 == ty and (c0+c)>>3 == tx exactly (r,c < 8), so the
  // swizzle XOR term is thread-uniform -> cheap addressing.
  float acc[8][8] = {};
#pragma unroll
  for (int ks = 0; ks < 16; ++ks) {
    float4 b[8];
    int sb = ((ks ^ tx) & 15) * 4;
#pragma unroll
    for (int c = 0; c < 8; ++c)
      b[c] = *(const float4*)&Zj[c0 + c][sb];
    int sa = ((ks ^ ty) & 15) * 4;
#pragma unroll
    for (int r = 0; r < 8; ++r) {
      float4 a = *(const float4*)&Zi[r0 + r][sa];
#pragma unroll
      for (int c = 0; c < 8; ++c)
        acc[r][c] += a.x * b[c].x + a.y * b[c].y + a.z * b[c].z + a.w * b[c].w;
    }
  }
  float sqa[8], sqb[8];
#pragma unroll
  for (int r = 0; r < 8; ++r) { int i = i0 + r0 + r; sqa[r] = (i < n) ? sq[i] : 0.f; }
#pragma unroll
  for (int c = 0; c < 8; ++c) { int j = j0 + c0 + c; sqb[c] = (j < n) ? sq[j] : 0.f; }
  float lmax = 0.f;
  bool interior = (i0 + 128 <= n) && (j0 + 128 <= n);
  if (interior) {
#pragma unroll
    for (int r = 0; r < 8; ++r) {
      size_t base = (size_t)(i0 + r0 + r) * n + (j0 + c0);
      float rowv[8];
#pragma unroll
      for (int c = 0; c < 8; ++c) {
        float d2 = sqa[r] + sqb[c] - 2.f * acc[r][c];
        float dd = (d2 > 0.f) ? sqrtf(d2) : 0.f;
        rowv[c] = dd;
        lmax = fmaxf(lmax, dd);
      }
      *(float4*)&dist[base]     = make_float4(rowv[0], rowv[1], rowv[2], rowv[3]);
      *(float4*)&dist[base + 4] = make_float4(rowv[4], rowv[5], rowv[6], rowv[7]);
    }
  } else {
    for (int r = 0; r < 8; ++r) {
      int i = i0 + r0 + r;
      if (i >= n) continue;
      for (int c = 0; c < 8; ++c) {
        int j = j0 + c0 + c;
        if (j >= n) continue;
        float d2 = sqa[r] + sqb[c] - 2.f * acc[r][c];
        float dd = (d2 > 0.f) ? sqrtf(d2) : 0.f;
        dist[(size_t)i * n + j] = dd;
        lmax = fmaxf(lmax, dd);
      }
    }
  }
#pragma unroll
  for (int o = 32; o > 0; o >>= 1) lmax = fmaxf(lmax, __shfl_xor(lmax, o, 64));
  if ((t & 63) == 0) atomicMax(gmax, __float_as_int(lmax));
}

// ---------------- decode pass 2: out = 1 - dist/m ----------------
__global__ void final_k(float* __restrict__ out, const int* __restrict__ gmax, size_t n2) {
  float m = __int_as_float(*gmax);
  float s = (m > 0.f) ? (1.f / m) : 0.f;
  size_t idx = (size_t)blockIdx.x * blockDim.x + threadIdx.x;
  size_t stride = (size_t)gridDim.x * blockDim.x;
  size_t n4 = n2 / 4;
  float4* o = (float4*)out;
  for (; idx < n4; idx += stride) {
    float4 v = o[idx];
    v.x = 1.f - v.x * s;
    v.y = 1.f - v.y * s;
    v.z = 1.f - v.z * s;
    v.w = 1.f - v.w * s;
    o[idx] = v;
  }
}

extern "C" void kernel_launch(void* const* d_in, const int* in_sizes, int n_in,
                              void* d_out, int out_size, void* d_ws, size_t ws_size,
                              hipStream_t stream) {
  const float* x  = (const float*)d_in[0];
  const int* eraw = (const int*)d_in[1];
  const float* W1 = (const float*)d_in[2];
  const float* b1 = (const float*)d_in[3];
  const float* W2 = (const float*)d_in[4];
  const float* b2 = (const float*)d_in[5];
  float* out = (float*)d_out;

  const int n = in_sizes[0] / D_IN;   // 10000
  const int E = in_sizes[1] / 2;      // 320000

  // workspace carve (256B aligned)
  char* p = (char*)d_ws;
  auto alloc = [&](size_t bytes) {
    void* r = (void*)p;
    p += (bytes + 255) & ~(size_t)255;
    return r;
  };
  int*   cnt      = (int*)alloc((size_t)n * 4);
  int*   offs     = (int*)alloc((size_t)(n + 1) * 4);
  int*   cursor   = (int*)alloc((size_t)n * 4);
  int*   esrc     = (int*)alloc((size_t)E * 4);
  int*   edst     = (int*)alloc((size_t)E * 4);
  int*   csr_src  = (int*)alloc((size_t)E * 4);
  float* csr_norm = (float*)alloc((size_t)E * 4);
  float* dinv     = (float*)alloc((size_t)n * 4);
  float* h        = (float*)alloc((size_t)n * D_H * 4);
  float* h1       = (float*)alloc((size_t)n * D_H * 4);
  float* h2      = (float*)alloc((size_t)n * D_OUT * 4);
  float* z        = (float*)alloc((size_t)n * D_OUT * 4);
  float* sq       = (float*)alloc((size_t)n * 4);
  int*   gmax     = (int*)alloc(4);

  init_k<<<64, 256, 0, stream>>>(cnt, cursor, gmax, n);
  edges_k<<<512, 256, 0, stream>>>(eraw, esrc, edst, E);
  count_k<<<512, 256, 0, stream>>>(edst, cnt, E);
  deg_k<<<(n + 255) / 256, 256, 0, stream>>>(cnt, dinv, n);
  scan_k<<<1, 1024, 0, stream>>>(cnt, offs, n);
  fill_k<<<512, 256, 0, stream>>>(esrc, edst, offs, cursor, dinv, csr_src, csr_norm, E);

  // layer 1
  gemm_k<<<dim3((n + 63) / 64, D_H / 64), 256, 0, stream>>>(x, W1, h, n, D_H, D_IN);
  agg1_k<<<(n + 3) / 4, 256, 0, stream>>>(h, offs, csr_src, csr_norm, dinv, b1, h1, n);

  // layer 2
  gemm_k<<<dim3((n + 63) / 64, D_OUT / 64), 256, 0, stream>>>(h1, W2, h2, n, D_OUT, D_H);
  agg2_k<<<(n + 3) / 4, 256, 0, stream>>>(h2, offs, csr_src, csr_norm, dinv, b2, z, sq, n);

  // decode
  int gt = (n + 127) / 128;
  decode_k<<<dim3(gt, gt), 256, 0, stream>>>(z, sq, out, gmax, n);
  final_k<<<2048, 256, 0, stream>>>(out, gmax, (size_t)n * n);
}

// Round 4
// 740.672 us; speedup vs baseline: 5.8998x; 2.7156x over previous
//
#include <hip/hip_runtime.h>
#include <hip/hip_bf16.h>
#include <cstdint>
#include <cstddef>

#define D_IN  128
#define D_H   256
#define D_OUT 64

// ---------------- init: zero counters ----------------
__global__ void init_k(int* cnt, int* cursor, int* gmax, int n) {
  int i = blockIdx.x * blockDim.x + threadIdx.x;
  int stride = gridDim.x * blockDim.x;
  for (; i < 2 * n + 1; i += stride) {
    if (i < n) cnt[i] = 0;
    else if (i < 2 * n) cursor[i - n] = 0;
    else gmax[0] = 0;
  }
}

// ---------------- extract edges (handles int32 or int64 storage) ----------------
__global__ void edges_k(const int* __restrict__ raw, int* __restrict__ src,
                        int* __restrict__ dst, int E) {
  __shared__ int flag;
  if (threadIdx.x == 0) {
    int zeros = 0;
    for (int i = 0; i < 64; ++i) zeros += (raw[2 * i + 1] == 0) ? 1 : 0;
    flag = (zeros >= 60) ? 1 : 0;  // int64: odd words are high halves == 0
  }
  __syncthreads();
  int is64 = flag;
  int idx = blockIdx.x * blockDim.x + threadIdx.x;
  int stride = gridDim.x * blockDim.x;
  for (; idx < E; idx += stride) {
    if (is64) {
      src[idx] = raw[2 * idx];
      dst[idx] = raw[2 * (E + idx)];
    } else {
      src[idx] = raw[idx];
      dst[idx] = raw[E + idx];
    }
  }
}

// ---------------- degree count ----------------
__global__ void count_k(const int* __restrict__ dst, int* cnt, int E) {
  int idx = blockIdx.x * blockDim.x + threadIdx.x;
  int stride = gridDim.x * blockDim.x;
  for (; idx < E; idx += stride) atomicAdd(&cnt[dst[idx]], 1);
}

// ---------------- dinv = rsqrt(deg+1) ----------------
__global__ void deg_k(const int* __restrict__ cnt, float* __restrict__ dinv, int n) {
  int i = blockIdx.x * blockDim.x + threadIdx.x;
  if (i < n) dinv[i] = rsqrtf((float)cnt[i] + 1.0f);
}

// ---------------- exclusive scan of cnt -> offsets (single block, n <= 10240) ----------------
__global__ void scan_k(const int* __restrict__ cnt, int* __restrict__ offs, int n) {
  __shared__ int sums[1024];
  int t = threadIdx.x;
  const int CH = 10;
  int base = t * CH;
  int local[CH];
  int s = 0;
  for (int i = 0; i < CH; ++i) {
    int v = (base + i < n) ? cnt[base + i] : 0;
    local[i] = s;
    s += v;
  }
  sums[t] = s;
  __syncthreads();
  for (int off = 1; off < 1024; off <<= 1) {
    int v = (t >= off) ? sums[t - off] : 0;
    __syncthreads();
    sums[t] += v;
    __syncthreads();
  }
  int prefix = (t > 0) ? sums[t - 1] : 0;
  for (int i = 0; i < CH; ++i)
    if (base + i < n) offs[base + i] = prefix + local[i];
  if (t == 1023) offs[n] = sums[1023];
}

// ---------------- fill CSR ----------------
__global__ void fill_k(const int* __restrict__ src, const int* __restrict__ dst,
                       const int* __restrict__ offs, int* __restrict__ cursor,
                       const float* __restrict__ dinv, int* __restrict__ csr_src,
                       float* __restrict__ csr_norm, int E) {
  int idx = blockIdx.x * blockDim.x + threadIdx.x;
  int stride = gridDim.x * blockDim.x;
  for (; idx < E; idx += stride) {
    int d = dst[idx], s = src[idx];
    int pos = atomicAdd(&cursor[d], 1);
    int slot = offs[d] + pos;
    csr_src[slot] = s;
    csr_norm[slot] = dinv[s] * dinv[d];
  }
}

// ---------------- generic fp32 tiled GEMM: C[M,N] = A[M,K] @ B[K,N] ----------------
__global__ void gemm_k(const float* __restrict__ A, const float* __restrict__ B,
                       float* __restrict__ C, int M, int N, int K) {
  __shared__ float As[16][64];
  __shared__ float Bs[16][64];
  int t = threadIdx.x;
  int bm = blockIdx.x * 64, bn = blockIdx.y * 64;
  int tx = t & 15, ty = t >> 4;
  int lr = t >> 2;            // A-load row 0..63
  int lk = (t & 3) * 4;       // A-load k offset
  int br = t >> 4;            // B-load k row 0..15
  int bc = (t & 15) * 4;      // B-load col offset
  float acc[4][4] = {};
  for (int k0 = 0; k0 < K; k0 += 16) {
    float4 av = make_float4(0.f, 0.f, 0.f, 0.f);
    if (bm + lr < M) av = *(const float4*)&A[(size_t)(bm + lr) * K + k0 + lk];
    As[lk + 0][lr] = av.x;
    As[lk + 1][lr] = av.y;
    As[lk + 2][lr] = av.z;
    As[lk + 3][lr] = av.w;
    float4 bv = *(const float4*)&B[(size_t)(k0 + br) * N + bn + bc];
    *(float4*)&Bs[br][bc] = bv;
    __syncthreads();
#pragma unroll
    for (int k = 0; k < 16; ++k) {
      float4 a = *(const float4*)&As[k][ty * 4];
      float4 b = *(const float4*)&Bs[k][tx * 4];
      acc[0][0] += a.x * b.x; acc[0][1] += a.x * b.y; acc[0][2] += a.x * b.z; acc[0][3] += a.x * b.w;
      acc[1][0] += a.y * b.x; acc[1][1] += a.y * b.y; acc[1][2] += a.y * b.z; acc[1][3] += a.y * b.w;
      acc[2][0] += a.z * b.x; acc[2][1] += a.z * b.y; acc[2][2] += a.z * b.z; acc[2][3] += a.z * b.w;
      acc[3][0] += a.w * b.x; acc[3][1] += a.w * b.y; acc[3][2] += a.w * b.z; acc[3][3] += a.w * b.w;
    }
    __syncthreads();
  }
  for (int r = 0; r < 4; ++r) {
    int row = bm + ty * 4 + r;
    if (row < M)
      *(float4*)&C[(size_t)row * N + bn + tx * 4] =
          make_float4(acc[r][0], acc[r][1], acc[r][2], acc[r][3]);
  }
}

// ---------------- GCN aggregation layer 1 (D_H=256), wave per node ----------------
__global__ void agg1_k(const float* __restrict__ h, const int* __restrict__ offs,
                       const int* __restrict__ csr_src, const float* __restrict__ csr_norm,
                       const float* __restrict__ dinv, const float* __restrict__ b1,
                       float* __restrict__ h1, int n) {
  int wid = blockIdx.x * 4 + (threadIdx.x >> 6);
  int lane = threadIdx.x & 63;
  if (wid >= n) return;
  float di = dinv[wid];
  float selfw = di * di;
  float4 acc = *(const float4*)&b1[lane * 4];
  float4 hv = *(const float4*)&h[(size_t)wid * D_H + lane * 4];
  acc.x += hv.x * selfw; acc.y += hv.y * selfw; acc.z += hv.z * selfw; acc.w += hv.w * selfw;
  int e0 = offs[wid], e1 = offs[wid + 1];
  for (int e = e0; e < e1; ++e) {
    int s = csr_src[e];
    float w = csr_norm[e];
    float4 v = *(const float4*)&h[(size_t)s * D_H + lane * 4];
    acc.x += v.x * w; acc.y += v.y * w; acc.z += v.z * w; acc.w += v.w * w;
  }
  acc.x = fmaxf(acc.x, 0.f); acc.y = fmaxf(acc.y, 0.f);
  acc.z = fmaxf(acc.z, 0.f); acc.w = fmaxf(acc.w, 0.f);
  *(float4*)&h1[(size_t)wid * D_H + lane * 4] = acc;
}

// ---------------- GCN aggregation layer 2 (D_OUT=64) + row sq, wave per node ----------------
__global__ void agg2_k(const float* __restrict__ h2, const int* __restrict__ offs,
                       const int* __restrict__ csr_src, const float* __restrict__ csr_norm,
                       const float* __restrict__ dinv, const float* __restrict__ b2,
                       float* __restrict__ z, float* __restrict__ sq, int n) {
  int wid = blockIdx.x * 4 + (threadIdx.x >> 6);
  int lane = threadIdx.x & 63;
  if (wid >= n) return;
  float di = dinv[wid];
  float selfw = di * di;
  float acc = b2[lane] + h2[(size_t)wid * D_OUT + lane] * selfw;
  int e0 = offs[wid], e1 = offs[wid + 1];
  for (int e = e0; e < e1; ++e) {
    int s = csr_src[e];
    float w = csr_norm[e];
    acc += h2[(size_t)s * D_OUT + lane] * w;
  }
  z[(size_t)wid * D_OUT + lane] = acc;
  float ss = acc * acc;
#pragma unroll
  for (int o = 32; o > 0; o >>= 1) ss += __shfl_xor(ss, o, 64);
  if (lane == 0) sq[wid] = ss;
}

// ---------------- decode pass 1: dist = sqrt(max(d2,0)), store + global max(dist) ----------------
// 128x128 tile, K=64 resident in LDS (XOR-swizzled float4 slots), 8x8 micro-tile.
// Semantics IDENTICAL to the round-2 kernel that passed (store dist, max over
// dist, separate final_k rescale). Only change vs R2: "#pragma unroll 1" on the
// ks loop — full unroll let the scheduler hoist ~256 LDS float4 loads, blowing
// the live set past 256 VGPRs and spilling acc to scratch (R1: 12 GB, R2:
// 6.5 GB HBM scratch traffic). Rolled loop keeps the live set ~120 VGPRs.
__global__ __launch_bounds__(256, 1) void decode_k(const float* __restrict__ Z,
                                                   const float* __restrict__ sq,
                                                   float* __restrict__ dist,
                                                   int* __restrict__ gmax, int n) {
  __shared__ float Zi[128][64];
  __shared__ float Zj[128][64];
  int t = threadIdx.x;
  int i0 = blockIdx.y * 128, j0 = blockIdx.x * 128;
#pragma unroll
  for (int it = 0; it < 8; ++it) {
    int idx = t + it * 256;
    int row = idx >> 4, slot = idx & 15;
    int sw = (slot ^ (row >> 3)) & 15;
    float4 v = make_float4(0.f, 0.f, 0.f, 0.f);
    if (i0 + row < n) v = *(const float4*)&Z[(size_t)(i0 + row) * D_OUT + slot * 4];
    *(float4*)&Zi[row][sw * 4] = v;
    float4 w = make_float4(0.f, 0.f, 0.f, 0.f);
    if (j0 + row < n) w = *(const float4*)&Z[(size_t)(j0 + row) * D_OUT + slot * 4];
    *(float4*)&Zj[row][sw * 4] = w;
  }
  __syncthreads();
  int tx = t & 15, ty = t >> 4;
  int r0 = ty * 8, c0 = tx * 8;
  // (r0+r)>>3 == ty and (c0+c)>>3 == tx exactly, so swizzle XOR is thread-uniform.
  float acc[8][8] = {};
#pragma unroll 1
  for (int ks = 0; ks < 16; ++ks) {
    float4 b[8];
    int sb = ((ks ^ tx) & 15) * 4;
#pragma unroll
    for (int c = 0; c < 8; ++c)
      b[c] = *(const float4*)&Zj[c0 + c][sb];
    int sa = ((ks ^ ty) & 15) * 4;
#pragma unroll
    for (int r = 0; r < 8; ++r) {
      float4 a = *(const float4*)&Zi[r0 + r][sa];
#pragma unroll
      for (int c = 0; c < 8; ++c)
        acc[r][c] += a.x * b[c].x + a.y * b[c].y + a.z * b[c].z + a.w * b[c].w;
    }
  }
  float sqa[8], sqb[8];
#pragma unroll
  for (int r = 0; r < 8; ++r) { int i = i0 + r0 + r; sqa[r] = (i < n) ? sq[i] : 0.f; }
#pragma unroll
  for (int c = 0; c < 8; ++c) { int j = j0 + c0 + c; sqb[c] = (j < n) ? sq[j] : 0.f; }
  float lmax = 0.f;
  bool interior = (i0 + 128 <= n) && (j0 + 128 <= n);
  if (interior) {
#pragma unroll
    for (int r = 0; r < 8; ++r) {
      size_t base = (size_t)(i0 + r0 + r) * n + (j0 + c0);
      float rowv[8];
#pragma unroll
      for (int c = 0; c < 8; ++c) {
        float d2 = sqa[r] + sqb[c] - 2.f * acc[r][c];
        float dd = (d2 > 0.f) ? sqrtf(d2) : 0.f;
        rowv[c] = dd;
        lmax = fmaxf(lmax, dd);
      }
      *(float4*)&dist[base]     = make_float4(rowv[0], rowv[1], rowv[2], rowv[3]);
      *(float4*)&dist[base + 4] = make_float4(rowv[4], rowv[5], rowv[6], rowv[7]);
    }
  } else {
    for (int r = 0; r < 8; ++r) {
      int i = i0 + r0 + r;
      if (i >= n) continue;
      for (int c = 0; c < 8; ++c) {
        int j = j0 + c0 + c;
        if (j >= n) continue;
        float d2 = sqa[r] + sqb[c] - 2.f * acc[r][c];
        float dd = (d2 > 0.f) ? sqrtf(d2) : 0.f;
        dist[(size_t)i * n + j] = dd;
        lmax = fmaxf(lmax, dd);
      }
    }
  }
#pragma unroll
  for (int o = 32; o > 0; o >>= 1) lmax = fmaxf(lmax, __shfl_xor(lmax, o, 64));
  if ((t & 63) == 0) atomicMax(gmax, __float_as_int(lmax));
}

// ---------------- decode pass 2: out = 1 - dist/m ----------------
__global__ void final_k(float* __restrict__ out, const int* __restrict__ gmax, size_t n2) {
  float m = __int_as_float(*gmax);
  float s = (m > 0.f) ? (1.f / m) : 0.f;
  size_t idx = (size_t)blockIdx.x * blockDim.x + threadIdx.x;
  size_t stride = (size_t)gridDim.x * blockDim.x;
  size_t n4 = n2 / 4;
  float4* o = (float4*)out;
  for (; idx < n4; idx += stride) {
    float4 v = o[idx];
    v.x = 1.f - v.x * s;
    v.y = 1.f - v.y * s;
    v.z = 1.f - v.z * s;
    v.w = 1.f - v.w * s;
    o[idx] = v;
  }
}

extern "C" void kernel_launch(void* const* d_in, const int* in_sizes, int n_in,
                              void* d_out, int out_size, void* d_ws, size_t ws_size,
                              hipStream_t stream) {
  const float* x  = (const float*)d_in[0];
  const int* eraw = (const int*)d_in[1];
  const float* W1 = (const float*)d_in[2];
  const float* b1 = (const float*)d_in[3];
  const float* W2 = (const float*)d_in[4];
  const float* b2 = (const float*)d_in[5];
  float* out = (float*)d_out;

  const int n = in_sizes[0] / D_IN;   // 10000
  const int E = in_sizes[1] / 2;      // 320000

  // workspace carve (256B aligned)
  char* p = (char*)d_ws;
  auto alloc = [&](size_t bytes) {
    void* r = (void*)p;
    p += (bytes + 255) & ~(size_t)255;
    return r;
  };
  int*   cnt      = (int*)alloc((size_t)n * 4);
  int*   offs     = (int*)alloc((size_t)(n + 1) * 4);
  int*   cursor   = (int*)alloc((size_t)n * 4);
  int*   esrc     = (int*)alloc((size_t)E * 4);
  int*   edst     = (int*)alloc((size_t)E * 4);
  int*   csr_src  = (int*)alloc((size_t)E * 4);
  float* csr_norm = (float*)alloc((size_t)E * 4);
  float* dinv     = (float*)alloc((size_t)n * 4);
  float* h        = (float*)alloc((size_t)n * D_H * 4);
  float* h1       = (float*)alloc((size_t)n * D_H * 4);
  float* h2       = (float*)alloc((size_t)n * D_OUT * 4);
  float* z        = (float*)alloc((size_t)n * D_OUT * 4);
  float* sq       = (float*)alloc((size_t)n * 4);
  int*   gmax     = (int*)alloc(4);

  init_k<<<64, 256, 0, stream>>>(cnt, cursor, gmax, n);
  edges_k<<<512, 256, 0, stream>>>(eraw, esrc, edst, E);
  count_k<<<512, 256, 0, stream>>>(edst, cnt, E);
  deg_k<<<(n + 255) / 256, 256, 0, stream>>>(cnt, dinv, n);
  scan_k<<<1, 1024, 0, stream>>>(cnt, offs, n);
  fill_k<<<512, 256, 0, stream>>>(esrc, edst, offs, cursor, dinv, csr_src, csr_norm, E);

  // layer 1
  gemm_k<<<dim3((n + 63) / 64, D_H / 64), 256, 0, stream>>>(x, W1, h, n, D_H, D_IN);
  agg1_k<<<(n + 3) / 4, 256, 0, stream>>>(h, offs, csr_src, csr_norm, dinv, b1, h1, n);

  // layer 2
  gemm_k<<<dim3((n + 63) / 64, D_OUT / 64), 256, 0, stream>>>(h1, W2, h2, n, D_OUT, D_H);
  agg2_k<<<(n + 3) / 4, 256, 0, stream>>>(h2, offs, csr_src, csr_norm, dinv, b2, z, sq, n);

  // decode: pass 1 = dist + global max(dist), pass 2 = out = 1 - dist/m
  int gt = (n + 127) / 128;
  decode_k<<<dim3(gt, gt), 256, 0, stream>>>(z, sq, out, gmax, n);
  final_k<<<2048, 256, 0, stream>>>(out, gmax, (size_t)n * n);
}

// Round 5
// 564.829 us; speedup vs baseline: 7.7365x; 1.3113x over previous
//
#include <hip/hip_runtime.h>
#include <hip/hip_bf16.h>
#include <cstdint>
#include <cstddef>

#define D_IN  128
#define D_H   256
#define D_OUT 64

typedef __attribute__((ext_vector_type(4))) float f32x4;
typedef __attribute__((ext_vector_type(8))) short s16x8;

// ---------------- init: zero counters ----------------
__global__ void init_k(int* cnt, int* cursor, int* gmax, int n) {
  int i = blockIdx.x * blockDim.x + threadIdx.x;
  int stride = gridDim.x * blockDim.x;
  for (; i < 2 * n + 1; i += stride) {
    if (i < n) cnt[i] = 0;
    else if (i < 2 * n) cursor[i - n] = 0;
    else gmax[0] = 0;
  }
}

// ---------------- zero the bf16-z padding rows [n, n_pad) ----------------
__global__ void pad_k(unsigned short* zb, int n, int n_pad) {
  int i = blockIdx.x * blockDim.x + threadIdx.x;
  int total = (n_pad - n) * D_OUT;
  if (i < total) zb[(size_t)n * D_OUT + i] = 0;
}

// ---------------- extract edges (handles int32 or int64 storage) ----------------
__global__ void edges_k(const int* __restrict__ raw, int* __restrict__ src,
                        int* __restrict__ dst, int E) {
  __shared__ int flag;
  if (threadIdx.x == 0) {
    int zeros = 0;
    for (int i = 0; i < 64; ++i) zeros += (raw[2 * i + 1] == 0) ? 1 : 0;
    flag = (zeros >= 60) ? 1 : 0;  // int64: odd words are high halves == 0
  }
  __syncthreads();
  int is64 = flag;
  int idx = blockIdx.x * blockDim.x + threadIdx.x;
  int stride = gridDim.x * blockDim.x;
  for (; idx < E; idx += stride) {
    if (is64) {
      src[idx] = raw[2 * idx];
      dst[idx] = raw[2 * (E + idx)];
    } else {
      src[idx] = raw[idx];
      dst[idx] = raw[E + idx];
    }
  }
}

// ---------------- degree count ----------------
__global__ void count_k(const int* __restrict__ dst, int* cnt, int E) {
  int idx = blockIdx.x * blockDim.x + threadIdx.x;
  int stride = gridDim.x * blockDim.x;
  for (; idx < E; idx += stride) atomicAdd(&cnt[dst[idx]], 1);
}

// ---------------- dinv = rsqrt(deg+1) ----------------
__global__ void deg_k(const int* __restrict__ cnt, float* __restrict__ dinv, int n) {
  int i = blockIdx.x * blockDim.x + threadIdx.x;
  if (i < n) dinv[i] = rsqrtf((float)cnt[i] + 1.0f);
}

// ---------------- exclusive scan of cnt -> offsets (single block, n <= 10240) ----------------
__global__ void scan_k(const int* __restrict__ cnt, int* __restrict__ offs, int n) {
  __shared__ int sums[1024];
  int t = threadIdx.x;
  const int CH = 10;
  int base = t * CH;
  int local[CH];
  int s = 0;
  for (int i = 0; i < CH; ++i) {
    int v = (base + i < n) ? cnt[base + i] : 0;
    local[i] = s;
    s += v;
  }
  sums[t] = s;
  __syncthreads();
  for (int off = 1; off < 1024; off <<= 1) {
    int v = (t >= off) ? sums[t - off] : 0;
    __syncthreads();
    sums[t] += v;
    __syncthreads();
  }
  int prefix = (t > 0) ? sums[t - 1] : 0;
  for (int i = 0; i < CH; ++i)
    if (base + i < n) offs[base + i] = prefix + local[i];
  if (t == 1023) offs[n] = sums[1023];
}

// ---------------- fill CSR ----------------
__global__ void fill_k(const int* __restrict__ src, const int* __restrict__ dst,
                       const int* __restrict__ offs, int* __restrict__ cursor,
                       const float* __restrict__ dinv, int* __restrict__ csr_src,
                       float* __restrict__ csr_norm, int E) {
  int idx = blockIdx.x * blockDim.x + threadIdx.x;
  int stride = gridDim.x * blockDim.x;
  for (; idx < E; idx += stride) {
    int d = dst[idx], s = src[idx];
    int pos = atomicAdd(&cursor[d], 1);
    int slot = offs[d] + pos;
    csr_src[slot] = s;
    csr_norm[slot] = dinv[s] * dinv[d];
  }
}

// ---------------- generic fp32 tiled GEMM: C[M,N] = A[M,K] @ B[K,N] ----------------
__global__ void gemm_k(const float* __restrict__ A, const float* __restrict__ B,
                       float* __restrict__ C, int M, int N, int K) {
  __shared__ float As[16][64];
  __shared__ float Bs[16][64];
  int t = threadIdx.x;
  int bm = blockIdx.x * 64, bn = blockIdx.y * 64;
  int tx = t & 15, ty = t >> 4;
  int lr = t >> 2;            // A-load row 0..63
  int lk = (t & 3) * 4;       // A-load k offset
  int br = t >> 4;            // B-load k row 0..15
  int bc = (t & 15) * 4;      // B-load col offset
  float acc[4][4] = {};
  for (int k0 = 0; k0 < K; k0 += 16) {
    float4 av = make_float4(0.f, 0.f, 0.f, 0.f);
    if (bm + lr < M) av = *(const float4*)&A[(size_t)(bm + lr) * K + k0 + lk];
    As[lk + 0][lr] = av.x;
    As[lk + 1][lr] = av.y;
    As[lk + 2][lr] = av.z;
    As[lk + 3][lr] = av.w;
    float4 bv = *(const float4*)&B[(size_t)(k0 + br) * N + bn + bc];
    *(float4*)&Bs[br][bc] = bv;
    __syncthreads();
#pragma unroll
    for (int k = 0; k < 16; ++k) {
      float4 a = *(const float4*)&As[k][ty * 4];
      float4 b = *(const float4*)&Bs[k][tx * 4];
      acc[0][0] += a.x * b.x; acc[0][1] += a.x * b.y; acc[0][2] += a.x * b.z; acc[0][3] += a.x * b.w;
      acc[1][0] += a.y * b.x; acc[1][1] += a.y * b.y; acc[1][2] += a.y * b.z; acc[1][3] += a.y * b.w;
      acc[2][0] += a.z * b.x; acc[2][1] += a.z * b.y; acc[2][2] += a.z * b.z; acc[2][3] += a.z * b.w;
      acc[3][0] += a.w * b.x; acc[3][1] += a.w * b.y; acc[3][2] += a.w * b.z; acc[3][3] += a.w * b.w;
    }
    __syncthreads();
  }
  for (int r = 0; r < 4; ++r) {
    int row = bm + ty * 4 + r;
    if (row < M)
      *(float4*)&C[(size_t)row * N + bn + tx * 4] =
          make_float4(acc[r][0], acc[r][1], acc[r][2], acc[r][3]);
  }
}

// ---------------- GCN aggregation layer 1 (D_H=256), wave per node ----------------
__global__ void agg1_k(const float* __restrict__ h, const int* __restrict__ offs,
                       const int* __restrict__ csr_src, const float* __restrict__ csr_norm,
                       const float* __restrict__ dinv, const float* __restrict__ b1,
                       float* __restrict__ h1, int n) {
  int wid = blockIdx.x * 4 + (threadIdx.x >> 6);
  int lane = threadIdx.x & 63;
  if (wid >= n) return;
  float di = dinv[wid];
  float selfw = di * di;
  float4 acc = *(const float4*)&b1[lane * 4];
  float4 hv = *(const float4*)&h[(size_t)wid * D_H + lane * 4];
  acc.x += hv.x * selfw; acc.y += hv.y * selfw; acc.z += hv.z * selfw; acc.w += hv.w * selfw;
  int e0 = offs[wid], e1 = offs[wid + 1];
  for (int e = e0; e < e1; ++e) {
    int s = csr_src[e];
    float w = csr_norm[e];
    float4 v = *(const float4*)&h[(size_t)s * D_H + lane * 4];
    acc.x += v.x * w; acc.y += v.y * w; acc.z += v.z * w; acc.w += v.w * w;
  }
  acc.x = fmaxf(acc.x, 0.f); acc.y = fmaxf(acc.y, 0.f);
  acc.z = fmaxf(acc.z, 0.f); acc.w = fmaxf(acc.w, 0.f);
  *(float4*)&h1[(size_t)wid * D_H + lane * 4] = acc;
}

// ---------------- GCN aggregation layer 2 (D_OUT=64): z->bf16, sq from ROUNDED z ----------------
// Rounding z to bf16 and computing sq from the rounded value makes
// d2 = sq_i + sq_j - 2*dot(zb_i,zb_j) = |zb_i - zb_j|^2 >= 0 exactly, so the
// bf16 MFMA decode error is a Lipschitz perturbation (|Δdist| <= 2||δz|| ~ 1e-2),
// not a cancellation blow-up.
__global__ void agg2_k(const float* __restrict__ h2, const int* __restrict__ offs,
                       const int* __restrict__ csr_src, const float* __restrict__ csr_norm,
                       const float* __restrict__ dinv, const float* __restrict__ b2,
                       unsigned short* __restrict__ zb, float* __restrict__ sq, int n) {
  int wid = blockIdx.x * 4 + (threadIdx.x >> 6);
  int lane = threadIdx.x & 63;
  if (wid >= n) return;
  float di = dinv[wid];
  float selfw = di * di;
  float acc = b2[lane] + h2[(size_t)wid * D_OUT + lane] * selfw;
  int e0 = offs[wid], e1 = offs[wid + 1];
  for (int e = e0; e < e1; ++e) {
    int s = csr_src[e];
    float w = csr_norm[e];
    acc += h2[(size_t)s * D_OUT + lane] * w;
  }
  // round-to-nearest-even to bf16
  unsigned u = __float_as_uint(acc);
  unsigned rb = (u + 0x7fffu + ((u >> 16) & 1u)) >> 16;
  zb[(size_t)wid * D_OUT + lane] = (unsigned short)rb;
  float back = __uint_as_float(rb << 16);
  float ss = back * back;
#pragma unroll
  for (int o = 32; o > 0; o >>= 1) ss += __shfl_xor(ss, o, 64);
  if (lane == 0) sq[wid] = ss;
}

// ---------------- MFMA decode: 128x128 tile, bf16 Z @ Z^T, K=64 ----------------
// 4 waves in 2x2, each wave a 64x64 panel = 4x4 tiles of 16x16 (mfma_f32_16x16x32_bf16).
// A and B frags use the IDENTICAL lane->(row,k) load pattern, so any error in the
// assumed A/B k-mapping cancels for Z@Z^T (MFMA pairs A's k-slot with B's same
// k-slot; any bijection over k gives the same dot product). C layout is the
// m89-verified col=lane&15, row=(lane>>4)*4+reg.
// LDS rows are 128 B; reads XOR-swizzled by ((row&7)<<4) so the 16 lanes of a
// row-group hit 8 distinct 16B slots (2-way alias = free).
// mode 0: global max of d2 over VALID cells only (i<n && j<n — the R3 bug was
// counting ghost cells where d2 = |z_j|^2). mode 1: out = 1 - sqrt(d2/m2).
__global__ __launch_bounds__(256, 1) void decode_mfma_k(
    const unsigned short* __restrict__ zb, const float* __restrict__ sq,
    float* __restrict__ out, int* __restrict__ gmax, int n, int mode) {
  __shared__ __align__(16) char ZiB[128 * 128];
  __shared__ __align__(16) char ZjB[128 * 128];
  __shared__ float sqi[128];
  __shared__ float sqj[128];
  int t = threadIdx.x;
  int i0 = blockIdx.y * 128, j0 = blockIdx.x * 128;

#pragma unroll
  for (int it = 0; it < 4; ++it) {
    int c = t + it * 256;          // 0..1023 chunks of 16B
    int row = c >> 3, s = c & 7;
    int dstb = row * 128 + ((s * 16) ^ ((row & 7) << 4));
    s16x8 vi = *(const s16x8*)&zb[(size_t)(i0 + row) * D_OUT + s * 8];
    *(s16x8*)&ZiB[dstb] = vi;
    s16x8 vj = *(const s16x8*)&zb[(size_t)(j0 + row) * D_OUT + s * 8];
    *(s16x8*)&ZjB[dstb] = vj;
  }
  if (t < 128) sqi[t] = (i0 + t < n) ? sq[i0 + t] : 0.f;
  else { int tt = t - 128; sqj[tt] = (j0 + tt < n) ? sq[j0 + tt] : 0.f; }
  __syncthreads();

  int lane = t & 63;
  int wid = t >> 6;
  int wr = (wid >> 1) * 64;        // wave panel offsets within tile
  int wc = (wid & 1) * 64;
  int lrow = lane & 15;
  int lgrp = lane >> 4;            // 0..3
  int swz = (lrow & 7) << 4;

  f32x4 acc[4][4] = {};
#pragma unroll
  for (int ks = 0; ks < 2; ++ks) {
    s16x8 a[4], b[4];
    int kb = (ks * 64) ^ (lgrp * 16) ^ swz;   // disjoint bit fields
#pragma unroll
    for (int q = 0; q < 4; ++q) {
      a[q] = *(const s16x8*)&ZiB[(wr + q * 16 + lrow) * 128 + kb];
      b[q] = *(const s16x8*)&ZjB[(wc + q * 16 + lrow) * 128 + kb];
    }
#pragma unroll
    for (int rt = 0; rt < 4; ++rt)
#pragma unroll
      for (int ct = 0; ct < 4; ++ct)
        acc[rt][ct] = __builtin_amdgcn_mfma_f32_16x16x32_bf16(a[rt], b[ct], acc[rt][ct], 0, 0, 0);
  }

  float sqa[4][4], sqb[4];
#pragma unroll
  for (int rt = 0; rt < 4; ++rt)
#pragma unroll
    for (int reg = 0; reg < 4; ++reg)
      sqa[rt][reg] = sqi[wr + rt * 16 + lgrp * 4 + reg];
#pragma unroll
  for (int ct = 0; ct < 4; ++ct) sqb[ct] = sqj[wc + ct * 16 + lrow];

  if (mode == 0) {
    float lmax = 0.f;
#pragma unroll
    for (int rt = 0; rt < 4; ++rt)
#pragma unroll
      for (int ct = 0; ct < 4; ++ct)
#pragma unroll
        for (int reg = 0; reg < 4; ++reg) {
          int i = i0 + wr + rt * 16 + lgrp * 4 + reg;
          int j = j0 + wc + ct * 16 + lrow;
          if (i < n && j < n) {   // EXCLUDE ghosts: d2_ghost = |z_valid|^2 > 0 (R3 bug)
            float d2 = sqa[rt][reg] + sqb[ct] - 2.f * acc[rt][ct][reg];
            lmax = fmaxf(lmax, d2);
          }
        }
#pragma unroll
    for (int o = 32; o > 0; o >>= 1) lmax = fmaxf(lmax, __shfl_xor(lmax, o, 64));
    if (lane == 0) atomicMax(gmax, __float_as_int(lmax));
  } else {
    float m2 = __int_as_float(*gmax);
    float inv = (m2 > 0.f) ? (1.f / m2) : 0.f;
#pragma unroll
    for (int rt = 0; rt < 4; ++rt)
#pragma unroll
      for (int reg = 0; reg < 4; ++reg) {
        int i = i0 + wr + rt * 16 + lgrp * 4 + reg;
        if (i >= n) continue;
        size_t rowbase = (size_t)i * n;
#pragma unroll
        for (int ct = 0; ct < 4; ++ct) {
          int j = j0 + wc + ct * 16 + lrow;
          if (j >= n) continue;
          float d2 = sqa[rt][reg] + sqb[ct] - 2.f * acc[rt][ct][reg];
          out[rowbase + j] = (d2 > 0.f) ? (1.f - sqrtf(d2 * inv)) : 1.f;
        }
      }
  }
}

extern "C" void kernel_launch(void* const* d_in, const int* in_sizes, int n_in,
                              void* d_out, int out_size, void* d_ws, size_t ws_size,
                              hipStream_t stream) {
  const float* x  = (const float*)d_in[0];
  const int* eraw = (const int*)d_in[1];
  const float* W1 = (const float*)d_in[2];
  const float* b1 = (const float*)d_in[3];
  const float* W2 = (const float*)d_in[4];
  const float* b2 = (const float*)d_in[5];
  float* out = (float*)d_out;

  const int n = in_sizes[0] / D_IN;   // 10000
  const int E = in_sizes[1] / 2;      // 320000
  const int gt = (n + 127) / 128;     // 79
  const int n_pad = gt * 128;         // 10112

  // workspace carve (256B aligned)
  char* p = (char*)d_ws;
  auto alloc = [&](size_t bytes) {
    void* r = (void*)p;
    p += (bytes + 255) & ~(size_t)255;
    return r;
  };
  int*   cnt      = (int*)alloc((size_t)n * 4);
  int*   offs     = (int*)alloc((size_t)(n + 1) * 4);
  int*   cursor   = (int*)alloc((size_t)n * 4);
  int*   esrc     = (int*)alloc((size_t)E * 4);
  int*   edst     = (int*)alloc((size_t)E * 4);
  int*   csr_src  = (int*)alloc((size_t)E * 4);
  float* csr_norm = (float*)alloc((size_t)E * 4);
  float* dinv     = (float*)alloc((size_t)n * 4);
  float* h        = (float*)alloc((size_t)n * D_H * 4);
  float* h1       = (float*)alloc((size_t)n * D_H * 4);
  float* h2       = (float*)alloc((size_t)n * D_OUT * 4);
  unsigned short* zbuf = (unsigned short*)alloc((size_t)n_pad * D_OUT * 2);
  float* sq       = (float*)alloc((size_t)n * 4);
  int*   gmax     = (int*)alloc(4);

  init_k<<<64, 256, 0, stream>>>(cnt, cursor, gmax, n);
  pad_k<<<((n_pad - n) * D_OUT + 255) / 256, 256, 0, stream>>>(zbuf, n, n_pad);
  edges_k<<<512, 256, 0, stream>>>(eraw, esrc, edst, E);
  count_k<<<512, 256, 0, stream>>>(edst, cnt, E);
  deg_k<<<(n + 255) / 256, 256, 0, stream>>>(cnt, dinv, n);
  scan_k<<<1, 1024, 0, stream>>>(cnt, offs, n);
  fill_k<<<512, 256, 0, stream>>>(esrc, edst, offs, cursor, dinv, csr_src, csr_norm, E);

  // layer 1
  gemm_k<<<dim3((n + 63) / 64, D_H / 64), 256, 0, stream>>>(x, W1, h, n, D_H, D_IN);
  agg1_k<<<(n + 3) / 4, 256, 0, stream>>>(h, offs, csr_src, csr_norm, dinv, b1, h1, n);

  // layer 2
  gemm_k<<<dim3((n + 63) / 64, D_OUT / 64), 256, 0, stream>>>(h1, W2, h2, n, D_OUT, D_H);
  agg2_k<<<(n + 3) / 4, 256, 0, stream>>>(h2, offs, csr_src, csr_norm, dinv, b2, zbuf, sq, n);

  // decode: pass 0 = global max(d2) (guarded), pass 1 = write 1 - sqrt(d2/m2)
  decode_mfma_k<<<dim3(gt, gt), 256, 0, stream>>>(zbuf, sq, out, gmax, n, 0);
  decode_mfma_k<<<dim3(gt, gt), 256, 0, stream>>>(zbuf, sq, out, gmax, n, 1);
}

// Round 6
// 305.251 us; speedup vs baseline: 14.3155x; 1.8504x over previous
//
#include <hip/hip_runtime.h>
#include <hip/hip_bf16.h>
#include <cstdint>
#include <cstddef>

#define D_IN  128
#define D_H   256
#define D_OUT 64

typedef __attribute__((ext_vector_type(4))) float f32x4;
typedef __attribute__((ext_vector_type(8))) short s16x8;

// ---------------- init: zero counters ----------------
__global__ void init_k(int* cnt, int* cursor, int* gmax, int n) {
  int i = blockIdx.x * blockDim.x + threadIdx.x;
  int stride = gridDim.x * blockDim.x;
  for (; i < 2 * n + 1; i += stride) {
    if (i < n) cnt[i] = 0;
    else if (i < 2 * n) cursor[i - n] = 0;
    else gmax[0] = 0;
  }
}

// ---------------- zero the bf16-z padding rows [n, n_pad) ----------------
__global__ void pad_k(unsigned short* zb, int n, int n_pad) {
  int i = blockIdx.x * blockDim.x + threadIdx.x;
  int total = (n_pad - n) * D_OUT;
  if (i < total) zb[(size_t)n * D_OUT + i] = 0;
}

// ---------------- extract edges (handles int32 or int64 storage) ----------------
__global__ void edges_k(const int* __restrict__ raw, int* __restrict__ src,
                        int* __restrict__ dst, int E) {
  __shared__ int flag;
  if (threadIdx.x == 0) {
    int zeros = 0;
    for (int i = 0; i < 64; ++i) zeros += (raw[2 * i + 1] == 0) ? 1 : 0;
    flag = (zeros >= 60) ? 1 : 0;  // int64: odd words are high halves == 0
  }
  __syncthreads();
  int is64 = flag;
  int idx = blockIdx.x * blockDim.x + threadIdx.x;
  int stride = gridDim.x * blockDim.x;
  for (; idx < E; idx += stride) {
    if (is64) {
      src[idx] = raw[2 * idx];
      dst[idx] = raw[2 * (E + idx)];
    } else {
      src[idx] = raw[idx];
      dst[idx] = raw[E + idx];
    }
  }
}

// ---------------- degree count ----------------
__global__ void count_k(const int* __restrict__ dst, int* cnt, int E) {
  int idx = blockIdx.x * blockDim.x + threadIdx.x;
  int stride = gridDim.x * blockDim.x;
  for (; idx < E; idx += stride) atomicAdd(&cnt[dst[idx]], 1);
}

// ---------------- dinv = rsqrt(deg+1) ----------------
__global__ void deg_k(const int* __restrict__ cnt, float* __restrict__ dinv, int n) {
  int i = blockIdx.x * blockDim.x + threadIdx.x;
  if (i < n) dinv[i] = rsqrtf((float)cnt[i] + 1.0f);
}

// ---------------- exclusive scan of cnt -> offsets (single block, n <= 10240) ----------------
__global__ void scan_k(const int* __restrict__ cnt, int* __restrict__ offs, int n) {
  __shared__ int sums[1024];
  int t = threadIdx.x;
  const int CH = 10;
  int base = t * CH;
  int local[CH];
  int s = 0;
  for (int i = 0; i < CH; ++i) {
    int v = (base + i < n) ? cnt[base + i] : 0;
    local[i] = s;
    s += v;
  }
  sums[t] = s;
  __syncthreads();
  for (int off = 1; off < 1024; off <<= 1) {
    int v = (t >= off) ? sums[t - off] : 0;
    __syncthreads();
    sums[t] += v;
    __syncthreads();
  }
  int prefix = (t > 0) ? sums[t - 1] : 0;
  for (int i = 0; i < CH; ++i)
    if (base + i < n) offs[base + i] = prefix + local[i];
  if (t == 1023) offs[n] = sums[1023];
}

// ---------------- fill CSR ----------------
__global__ void fill_k(const int* __restrict__ src, const int* __restrict__ dst,
                       const int* __restrict__ offs, int* __restrict__ cursor,
                       const float* __restrict__ dinv, int* __restrict__ csr_src,
                       float* __restrict__ csr_norm, int E) {
  int idx = blockIdx.x * blockDim.x + threadIdx.x;
  int stride = gridDim.x * blockDim.x;
  for (; idx < E; idx += stride) {
    int d = dst[idx], s = src[idx];
    int pos = atomicAdd(&cursor[d], 1);
    int slot = offs[d] + pos;
    csr_src[slot] = s;
    csr_norm[slot] = dinv[s] * dinv[d];
  }
}

// ---------------- generic fp32 tiled GEMM: C[M,N] = A[M,K] @ B[K,N] ----------------
__global__ void gemm_k(const float* __restrict__ A, const float* __restrict__ B,
                       float* __restrict__ C, int M, int N, int K) {
  __shared__ float As[16][64];
  __shared__ float Bs[16][64];
  int t = threadIdx.x;
  int bm = blockIdx.x * 64, bn = blockIdx.y * 64;
  int tx = t & 15, ty = t >> 4;
  int lr = t >> 2;            // A-load row 0..63
  int lk = (t & 3) * 4;       // A-load k offset
  int br = t >> 4;            // B-load k row 0..15
  int bc = (t & 15) * 4;      // B-load col offset
  float acc[4][4] = {};
  for (int k0 = 0; k0 < K; k0 += 16) {
    float4 av = make_float4(0.f, 0.f, 0.f, 0.f);
    if (bm + lr < M) av = *(const float4*)&A[(size_t)(bm + lr) * K + k0 + lk];
    As[lk + 0][lr] = av.x;
    As[lk + 1][lr] = av.y;
    As[lk + 2][lr] = av.z;
    As[lk + 3][lr] = av.w;
    float4 bv = *(const float4*)&B[(size_t)(k0 + br) * N + bn + bc];
    *(float4*)&Bs[br][bc] = bv;
    __syncthreads();
#pragma unroll
    for (int k = 0; k < 16; ++k) {
      float4 a = *(const float4*)&As[k][ty * 4];
      float4 b = *(const float4*)&Bs[k][tx * 4];
      acc[0][0] += a.x * b.x; acc[0][1] += a.x * b.y; acc[0][2] += a.x * b.z; acc[0][3] += a.x * b.w;
      acc[1][0] += a.y * b.x; acc[1][1] += a.y * b.y; acc[1][2] += a.y * b.z; acc[1][3] += a.y * b.w;
      acc[2][0] += a.z * b.x; acc[2][1] += a.z * b.y; acc[2][2] += a.z * b.z; acc[2][3] += a.z * b.w;
      acc[3][0] += a.w * b.x; acc[3][1] += a.w * b.y; acc[3][2] += a.w * b.z; acc[3][3] += a.w * b.w;
    }
    __syncthreads();
  }
  for (int r = 0; r < 4; ++r) {
    int row = bm + ty * 4 + r;
    if (row < M)
      *(float4*)&C[(size_t)row * N + bn + tx * 4] =
          make_float4(acc[r][0], acc[r][1], acc[r][2], acc[r][3]);
  }
}

// ---------------- GCN aggregation layer 1 (D_H=256), wave per node ----------------
__global__ void agg1_k(const float* __restrict__ h, const int* __restrict__ offs,
                       const int* __restrict__ csr_src, const float* __restrict__ csr_norm,
                       const float* __restrict__ dinv, const float* __restrict__ b1,
                       float* __restrict__ h1, int n) {
  int wid = blockIdx.x * 4 + (threadIdx.x >> 6);
  int lane = threadIdx.x & 63;
  if (wid >= n) return;
  float di = dinv[wid];
  float selfw = di * di;
  float4 acc = *(const float4*)&b1[lane * 4];
  float4 hv = *(const float4*)&h[(size_t)wid * D_H + lane * 4];
  acc.x += hv.x * selfw; acc.y += hv.y * selfw; acc.z += hv.z * selfw; acc.w += hv.w * selfw;
  int e0 = offs[wid], e1 = offs[wid + 1];
  for (int e = e0; e < e1; ++e) {
    int s = csr_src[e];
    float w = csr_norm[e];
    float4 v = *(const float4*)&h[(size_t)s * D_H + lane * 4];
    acc.x += v.x * w; acc.y += v.y * w; acc.z += v.z * w; acc.w += v.w * w;
  }
  acc.x = fmaxf(acc.x, 0.f); acc.y = fmaxf(acc.y, 0.f);
  acc.z = fmaxf(acc.z, 0.f); acc.w = fmaxf(acc.w, 0.f);
  *(float4*)&h1[(size_t)wid * D_H + lane * 4] = acc;
}

// ---------------- GCN aggregation layer 2 (D_OUT=64): z->bf16, sq from ROUNDED z ----------------
// sq computed from the bf16-rounded z makes d2 = |zb_i - zb_j|^2 exactly, so
// the bf16 MFMA decode is a Lipschitz perturbation, not a cancellation blow-up.
__global__ void agg2_k(const float* __restrict__ h2, const int* __restrict__ offs,
                       const int* __restrict__ csr_src, const float* __restrict__ csr_norm,
                       const float* __restrict__ dinv, const float* __restrict__ b2,
                       unsigned short* __restrict__ zb, float* __restrict__ sq, int n) {
  int wid = blockIdx.x * 4 + (threadIdx.x >> 6);
  int lane = threadIdx.x & 63;
  if (wid >= n) return;
  float di = dinv[wid];
  float selfw = di * di;
  float acc = b2[lane] + h2[(size_t)wid * D_OUT + lane] * selfw;
  int e0 = offs[wid], e1 = offs[wid + 1];
  for (int e = e0; e < e1; ++e) {
    int s = csr_src[e];
    float w = csr_norm[e];
    acc += h2[(size_t)s * D_OUT + lane] * w;
  }
  // round-to-nearest-even to bf16
  unsigned u = __float_as_uint(acc);
  unsigned rb = (u + 0x7fffu + ((u >> 16) & 1u)) >> 16;
  zb[(size_t)wid * D_OUT + lane] = (unsigned short)rb;
  float back = __uint_as_float(rb << 16);
  float ss = back * back;
#pragma unroll
  for (int o = 32; o > 0; o >>= 1) ss += __shfl_xor(ss, o, 64);
  if (lane == 0) sq[wid] = ss;
}

// ---------------- MFMA decode: 128x128 tile, bf16 Z @ Z^T, K=64 ----------------
// mode 0: per-block max(d2) -> blockmax[bid] via PLAIN STORE. R5 counters showed
// the old single-address atomicMax (25K waves -> 1 cacheline) serialized for
// ~260 us with all pipes idle (MfmaUtil 1.75%, VALUBusy 8%, no memory traffic).
// Disjoint stores + a 5-us tree-reduce kernel replace it.
// mode 1: out = 1 - sqrt(d2/m2), reading gmax produced by reduce_k.
__global__ __launch_bounds__(256, 1) void decode_mfma_k(
    const unsigned short* __restrict__ zb, const float* __restrict__ sq,
    float* __restrict__ out, float* __restrict__ blockmax,
    const int* __restrict__ gmax, int n, int mode) {
  __shared__ __align__(16) char ZiB[128 * 128];
  __shared__ __align__(16) char ZjB[128 * 128];
  __shared__ float sqi[128];
  __shared__ float sqj[128];
  __shared__ float wmax[4];
  int t = threadIdx.x;
  int i0 = blockIdx.y * 128, j0 = blockIdx.x * 128;

#pragma unroll
  for (int it = 0; it < 4; ++it) {
    int c = t + it * 256;          // 0..1023 chunks of 16B
    int row = c >> 3, s = c & 7;
    int dstb = row * 128 + ((s * 16) ^ ((row & 7) << 4));
    s16x8 vi = *(const s16x8*)&zb[(size_t)(i0 + row) * D_OUT + s * 8];
    *(s16x8*)&ZiB[dstb] = vi;
    s16x8 vj = *(const s16x8*)&zb[(size_t)(j0 + row) * D_OUT + s * 8];
    *(s16x8*)&ZjB[dstb] = vj;
  }
  if (t < 128) sqi[t] = (i0 + t < n) ? sq[i0 + t] : 0.f;
  else { int tt = t - 128; sqj[tt] = (j0 + tt < n) ? sq[j0 + tt] : 0.f; }
  __syncthreads();

  int lane = t & 63;
  int wid = t >> 6;
  int wr = (wid >> 1) * 64;        // wave panel offsets within tile
  int wc = (wid & 1) * 64;
  int lrow = lane & 15;
  int lgrp = lane >> 4;            // 0..3
  int swz = (lrow & 7) << 4;

  f32x4 acc[4][4] = {};
#pragma unroll
  for (int ks = 0; ks < 2; ++ks) {
    s16x8 a[4], b[4];
    int kb = (ks * 64) ^ (lgrp * 16) ^ swz;   // disjoint bit fields
#pragma unroll
    for (int q = 0; q < 4; ++q) {
      a[q] = *(const s16x8*)&ZiB[(wr + q * 16 + lrow) * 128 + kb];
      b[q] = *(const s16x8*)&ZjB[(wc + q * 16 + lrow) * 128 + kb];
    }
#pragma unroll
    for (int rt = 0; rt < 4; ++rt)
#pragma unroll
      for (int ct = 0; ct < 4; ++ct)
        acc[rt][ct] = __builtin_amdgcn_mfma_f32_16x16x32_bf16(a[rt], b[ct], acc[rt][ct], 0, 0, 0);
  }

  float sqa[4][4], sqb[4];
#pragma unroll
  for (int rt = 0; rt < 4; ++rt)
#pragma unroll
    for (int reg = 0; reg < 4; ++reg)
      sqa[rt][reg] = sqi[wr + rt * 16 + lgrp * 4 + reg];
#pragma unroll
  for (int ct = 0; ct < 4; ++ct) sqb[ct] = sqj[wc + ct * 16 + lrow];

  if (mode == 0) {
    float lmax = 0.f;
#pragma unroll
    for (int rt = 0; rt < 4; ++rt)
#pragma unroll
      for (int ct = 0; ct < 4; ++ct)
#pragma unroll
        for (int reg = 0; reg < 4; ++reg) {
          int i = i0 + wr + rt * 16 + lgrp * 4 + reg;
          int j = j0 + wc + ct * 16 + lrow;
          if (i < n && j < n) {   // EXCLUDE ghosts: d2_ghost = |z_valid|^2 > 0 (R3 bug)
            float d2 = sqa[rt][reg] + sqb[ct] - 2.f * acc[rt][ct][reg];
            lmax = fmaxf(lmax, d2);
          }
        }
#pragma unroll
    for (int o = 32; o > 0; o >>= 1) lmax = fmaxf(lmax, __shfl_xor(lmax, o, 64));
    if (lane == 0) wmax[wid] = lmax;
    __syncthreads();
    if (t == 0) {
      float m = fmaxf(fmaxf(wmax[0], wmax[1]), fmaxf(wmax[2], wmax[3]));
      blockmax[blockIdx.y * gridDim.x + blockIdx.x] = m;  // disjoint store, no atomic
    }
  } else {
    float m2 = __int_as_float(*gmax);
    float inv = (m2 > 0.f) ? (1.f / m2) : 0.f;
#pragma unroll
    for (int rt = 0; rt < 4; ++rt)
#pragma unroll
      for (int reg = 0; reg < 4; ++reg) {
        int i = i0 + wr + rt * 16 + lgrp * 4 + reg;
        if (i >= n) continue;
        size_t rowbase = (size_t)i * n;
#pragma unroll
        for (int ct = 0; ct < 4; ++ct) {
          int j = j0 + wc + ct * 16 + lrow;
          if (j >= n) continue;
          float d2 = sqa[rt][reg] + sqb[ct] - 2.f * acc[rt][ct][reg];
          out[rowbase + j] = (d2 > 0.f) ? (1.f - sqrtf(d2 * inv)) : 1.f;
        }
      }
  }
}

// ---------------- reduce 6241 block maxes -> gmax (single block) ----------------
__global__ void reduce_k(const float* __restrict__ bm, int* __restrict__ gmax, int nb) {
  __shared__ float s[1024];
  int t = threadIdx.x;
  float m = 0.f;
  for (int i = t; i < nb; i += 1024) m = fmaxf(m, bm[i]);
  s[t] = m;
  __syncthreads();
  for (int o = 512; o > 0; o >>= 1) {
    if (t < o) s[t] = fmaxf(s[t], s[t + o]);
    __syncthreads();
  }
  if (t == 0) gmax[0] = __float_as_int(s[0]);
}

extern "C" void kernel_launch(void* const* d_in, const int* in_sizes, int n_in,
                              void* d_out, int out_size, void* d_ws, size_t ws_size,
                              hipStream_t stream) {
  const float* x  = (const float*)d_in[0];
  const int* eraw = (const int*)d_in[1];
  const float* W1 = (const float*)d_in[2];
  const float* b1 = (const float*)d_in[3];
  const float* W2 = (const float*)d_in[4];
  const float* b2 = (const float*)d_in[5];
  float* out = (float*)d_out;

  const int n = in_sizes[0] / D_IN;   // 10000
  const int E = in_sizes[1] / 2;      // 320000
  const int gt = (n + 127) / 128;     // 79
  const int n_pad = gt * 128;         // 10112

  // workspace carve (256B aligned)
  char* p = (char*)d_ws;
  auto alloc = [&](size_t bytes) {
    void* r = (void*)p;
    p += (bytes + 255) & ~(size_t)255;
    return r;
  };
  int*   cnt      = (int*)alloc((size_t)n * 4);
  int*   offs     = (int*)alloc((size_t)(n + 1) * 4);
  int*   cursor   = (int*)alloc((size_t)n * 4);
  int*   esrc     = (int*)alloc((size_t)E * 4);
  int*   edst     = (int*)alloc((size_t)E * 4);
  int*   csr_src  = (int*)alloc((size_t)E * 4);
  float* csr_norm = (float*)alloc((size_t)E * 4);
  float* dinv     = (float*)alloc((size_t)n * 4);
  float* h        = (float*)alloc((size_t)n * D_H * 4);
  float* h1       = (float*)alloc((size_t)n * D_H * 4);
  float* h2       = (float*)alloc((size_t)n * D_OUT * 4);
  unsigned short* zbuf = (unsigned short*)alloc((size_t)n_pad * D_OUT * 2);
  float* sq       = (float*)alloc((size_t)n * 4);
  float* blockmax = (float*)alloc((size_t)gt * gt * 4);
  int*   gmax     = (int*)alloc(4);

  init_k<<<64, 256, 0, stream>>>(cnt, cursor, gmax, n);
  pad_k<<<((n_pad - n) * D_OUT + 255) / 256, 256, 0, stream>>>(zbuf, n, n_pad);
  edges_k<<<512, 256, 0, stream>>>(eraw, esrc, edst, E);
  count_k<<<512, 256, 0, stream>>>(edst, cnt, E);
  deg_k<<<(n + 255) / 256, 256, 0, stream>>>(cnt, dinv, n);
  scan_k<<<1, 1024, 0, stream>>>(cnt, offs, n);
  fill_k<<<512, 256, 0, stream>>>(esrc, edst, offs, cursor, dinv, csr_src, csr_norm, E);

  // layer 1
  gemm_k<<<dim3((n + 63) / 64, D_H / 64), 256, 0, stream>>>(x, W1, h, n, D_H, D_IN);
  agg1_k<<<(n + 3) / 4, 256, 0, stream>>>(h, offs, csr_src, csr_norm, dinv, b1, h1, n);

  // layer 2
  gemm_k<<<dim3((n + 63) / 64, D_OUT / 64), 256, 0, stream>>>(h1, W2, h2, n, D_OUT, D_H);
  agg2_k<<<(n + 3) / 4, 256, 0, stream>>>(h2, offs, csr_src, csr_norm, dinv, b2, zbuf, sq, n);

  // decode: pass 0 = per-block max(d2), reduce, pass 1 = write 1 - sqrt(d2/m2)
  decode_mfma_k<<<dim3(gt, gt), 256, 0, stream>>>(zbuf, sq, out, blockmax, gmax, n, 0);
  reduce_k<<<1, 1024, 0, stream>>>(blockmax, gmax, gt * gt);
  decode_mfma_k<<<dim3(gt, gt), 256, 0, stream>>>(zbuf, sq, out, blockmax, gmax, n, 1);
}

// Round 7
// 275.504 us; speedup vs baseline: 15.8612x; 1.1080x over previous
//
#include <hip/hip_runtime.h>
#include <hip/hip_bf16.h>
#include <cstdint>
#include <cstddef>

#define D_IN  128
#define D_H   256
#define D_OUT 64

typedef __attribute__((ext_vector_type(4))) float f32x4;
typedef __attribute__((ext_vector_type(8))) short s16x8;

__device__ __forceinline__ unsigned short f2bf(float f) {
  unsigned u = __float_as_uint(f);
  return (unsigned short)((u + 0x7fffu + ((u >> 16) & 1u)) >> 16);
}
__device__ __forceinline__ float bf2f(unsigned short b) {
  return __uint_as_float(((unsigned)b) << 16);
}

// ---------------- fused prep: zero counters, pad zb, extract edges ----------------
__global__ void prep_k(const int* __restrict__ raw, int* __restrict__ cnt,
                       int* __restrict__ cursor, int* __restrict__ gmax,
                       unsigned short* __restrict__ zb, int* __restrict__ src,
                       int* __restrict__ dst, int n, int npadElems, int E) {
  __shared__ int flag;
  if (threadIdx.x == 0) {
    int zeros = 0;
    for (int i = 0; i < 64; ++i) zeros += (raw[2 * i + 1] == 0) ? 1 : 0;
    flag = (zeros >= 60) ? 1 : 0;  // int64 storage: odd words are zero high halves
  }
  __syncthreads();
  int is64 = flag;
  int T = n + 1 + npadElems + E;
  int idx = blockIdx.x * blockDim.x + threadIdx.x;
  int stride = gridDim.x * blockDim.x;
  for (; idx < T; idx += stride) {
    if (idx < n) { cnt[idx] = 0; cursor[idx] = 0; }
    else if (idx == n) gmax[0] = 0;
    else if (idx < n + 1 + npadElems) zb[(size_t)n * D_OUT + (idx - (n + 1))] = 0;
    else {
      int e = idx - (n + 1 + npadElems);
      if (is64) { src[e] = raw[2 * e]; dst[e] = raw[2 * (E + e)]; }
      else      { src[e] = raw[e];     dst[e] = raw[E + e]; }
    }
  }
}

// ---------------- degree count ----------------
__global__ void count_k(const int* __restrict__ dst, int* cnt, int E) {
  int idx = blockIdx.x * blockDim.x + threadIdx.x;
  int stride = gridDim.x * blockDim.x;
  for (; idx < E; idx += stride) atomicAdd(&cnt[dst[idx]], 1);
}

// ---------------- exclusive scan of cnt -> offs; dinv = rsqrt(cnt+1) fused ----------------
__global__ void scan_k(const int* __restrict__ cnt, int* __restrict__ offs,
                       float* __restrict__ dinv, int n) {
  __shared__ int sums[1024];
  int t = threadIdx.x;
  const int CH = 10;
  int base = t * CH;
  int local[CH];
  int s = 0;
  for (int i = 0; i < CH; ++i) {
    int v = (base + i < n) ? cnt[base + i] : 0;
    if (base + i < n) dinv[base + i] = rsqrtf((float)v + 1.0f);
    local[i] = s;
    s += v;
  }
  sums[t] = s;
  __syncthreads();
  for (int off = 1; off < 1024; off <<= 1) {
    int v = (t >= off) ? sums[t - off] : 0;
    __syncthreads();
    sums[t] += v;
    __syncthreads();
  }
  int prefix = (t > 0) ? sums[t - 1] : 0;
  for (int i = 0; i < CH; ++i)
    if (base + i < n) offs[base + i] = prefix + local[i];
  if (t == 1023) offs[n] = sums[1023];
}

// ---------------- fill CSR ----------------
__global__ void fill_k(const int* __restrict__ src, const int* __restrict__ dst,
                       const int* __restrict__ offs, int* __restrict__ cursor,
                       const float* __restrict__ dinv, int* __restrict__ csr_src,
                       float* __restrict__ csr_norm, int E) {
  int idx = blockIdx.x * blockDim.x + threadIdx.x;
  int stride = gridDim.x * blockDim.x;
  for (; idx < E; idx += stride) {
    int d = dst[idx], s = src[idx];
    int pos = atomicAdd(&cursor[d], 1);
    int slot = offs[d] + pos;
    csr_src[slot] = s;
    csr_norm[slot] = dinv[s] * dinv[d];
  }
}

// ---------------- layer-1 GEMM: C[M,N] = A[M,K] @ B[K,N], bf16 OUTPUT ----------------
// BM=BN=64, BK=16, 256 threads, 4x4 micro-tile. bf16 store halves h traffic for
// agg1's 327MB gather; 33-term aggregation RMS-averages the rounding (~2e-4 eff).
__global__ void gemm1_k(const float* __restrict__ A, const float* __restrict__ B,
                        unsigned short* __restrict__ C, int M, int N, int K) {
  __shared__ float As[16][64];
  __shared__ float Bs[16][64];
  int t = threadIdx.x;
  int bm = blockIdx.x * 64, bn = blockIdx.y * 64;
  int tx = t & 15, ty = t >> 4;
  int lr = t >> 2;
  int lk = (t & 3) * 4;
  int br = t >> 4;
  int bc = (t & 15) * 4;
  float acc[4][4] = {};
  for (int k0 = 0; k0 < K; k0 += 16) {
    float4 av = make_float4(0.f, 0.f, 0.f, 0.f);
    if (bm + lr < M) av = *(const float4*)&A[(size_t)(bm + lr) * K + k0 + lk];
    As[lk + 0][lr] = av.x;
    As[lk + 1][lr] = av.y;
    As[lk + 2][lr] = av.z;
    As[lk + 3][lr] = av.w;
    float4 bv = *(const float4*)&B[(size_t)(k0 + br) * N + bn + bc];
    *(float4*)&Bs[br][bc] = bv;
    __syncthreads();
#pragma unroll
    for (int k = 0; k < 16; ++k) {
      float4 a = *(const float4*)&As[k][ty * 4];
      float4 b = *(const float4*)&Bs[k][tx * 4];
      acc[0][0] += a.x * b.x; acc[0][1] += a.x * b.y; acc[0][2] += a.x * b.z; acc[0][3] += a.x * b.w;
      acc[1][0] += a.y * b.x; acc[1][1] += a.y * b.y; acc[1][2] += a.y * b.z; acc[1][3] += a.y * b.w;
      acc[2][0] += a.z * b.x; acc[2][1] += a.z * b.y; acc[2][2] += a.z * b.z; acc[2][3] += a.z * b.w;
      acc[3][0] += a.w * b.x; acc[3][1] += a.w * b.y; acc[3][2] += a.w * b.z; acc[3][3] += a.w * b.w;
    }
    __syncthreads();
  }
  for (int r = 0; r < 4; ++r) {
    int row = bm + ty * 4 + r;
    if (row < M) {
      ushort4 o;
      o.x = f2bf(acc[r][0]); o.y = f2bf(acc[r][1]);
      o.z = f2bf(acc[r][2]); o.w = f2bf(acc[r][3]);
      *(ushort4*)&C[(size_t)row * N + bn + tx * 4] = o;
    }
  }
}

// ---------------- layer-2 GEMM: BM=32,BN=64,BK=16 -> 313 blocks (fills 256 CUs) ----------------
// The 64x64-tile version had only 157 blocks for 256 CUs (latency-bound).
__global__ void gemm2_k(const float* __restrict__ A, const float* __restrict__ B,
                        float* __restrict__ C, int M, int N, int K) {
  __shared__ float As[16][32];
  __shared__ float Bs[16][64];
  int t = threadIdx.x;
  int bm = blockIdx.x * 32;
  int tx = t & 15, ty = t >> 4;       // ty 0..15 -> 2 rows each; tx -> 4 cols
  int lr = t >> 3;                    // A-load row 0..31
  int lkk = (t & 7) * 2;              // A-load k offset (float2)
  int br = t >> 4;                    // B-load k row 0..15
  int bc = (t & 15) * 4;              // B-load col
  float acc[2][4] = {};
  for (int k0 = 0; k0 < K; k0 += 16) {
    float2 av = make_float2(0.f, 0.f);
    if (bm + lr < M) av = *(const float2*)&A[(size_t)(bm + lr) * K + k0 + lkk];
    As[lkk + 0][lr] = av.x;
    As[lkk + 1][lr] = av.y;
    float4 bv = *(const float4*)&B[(size_t)(k0 + br) * N + bc];
    *(float4*)&Bs[br][bc] = bv;
    __syncthreads();
#pragma unroll
    for (int k = 0; k < 16; ++k) {
      float a0 = As[k][ty * 2], a1 = As[k][ty * 2 + 1];
      float4 b = *(const float4*)&Bs[k][tx * 4];
      acc[0][0] += a0 * b.x; acc[0][1] += a0 * b.y; acc[0][2] += a0 * b.z; acc[0][3] += a0 * b.w;
      acc[1][0] += a1 * b.x; acc[1][1] += a1 * b.y; acc[1][2] += a1 * b.z; acc[1][3] += a1 * b.w;
    }
    __syncthreads();
  }
  for (int r = 0; r < 2; ++r) {
    int row = bm + ty * 2 + r;
    if (row < M)
      *(float4*)&C[(size_t)row * N + tx * 4] =
          make_float4(acc[r][0], acc[r][1], acc[r][2], acc[r][3]);
  }
}

// ---------------- GCN aggregation layer 1 (D_H=256), wave per node, bf16 h ----------------
__global__ void agg1_k(const unsigned short* __restrict__ hb, const int* __restrict__ offs,
                       const int* __restrict__ csr_src, const float* __restrict__ csr_norm,
                       const float* __restrict__ dinv, const float* __restrict__ b1,
                       float* __restrict__ h1, int n) {
  int wid = blockIdx.x * 4 + (threadIdx.x >> 6);
  int lane = threadIdx.x & 63;
  if (wid >= n) return;
  const ushort4* hb4 = (const ushort4*)hb;
  float di = dinv[wid];
  float selfw = di * di;
  float4 acc = *(const float4*)&b1[lane * 4];
  ushort4 sv = hb4[(size_t)wid * 64 + lane];
  acc.x += bf2f(sv.x) * selfw; acc.y += bf2f(sv.y) * selfw;
  acc.z += bf2f(sv.z) * selfw; acc.w += bf2f(sv.w) * selfw;
  int e0 = offs[wid], e1 = offs[wid + 1];
  for (int e = e0; e < e1; ++e) {
    int s = csr_src[e];
    float w = csr_norm[e];
    ushort4 v = hb4[(size_t)s * 64 + lane];
    acc.x += bf2f(v.x) * w; acc.y += bf2f(v.y) * w;
    acc.z += bf2f(v.z) * w; acc.w += bf2f(v.w) * w;
  }
  acc.x = fmaxf(acc.x, 0.f); acc.y = fmaxf(acc.y, 0.f);
  acc.z = fmaxf(acc.z, 0.f); acc.w = fmaxf(acc.w, 0.f);
  *(float4*)&h1[(size_t)wid * D_H + lane * 4] = acc;
}

// ---------------- GCN aggregation layer 2 (D_OUT=64): z->bf16, sq from ROUNDED z ----------------
__global__ void agg2_k(const float* __restrict__ h2, const int* __restrict__ offs,
                       const int* __restrict__ csr_src, const float* __restrict__ csr_norm,
                       const float* __restrict__ dinv, const float* __restrict__ b2,
                       unsigned short* __restrict__ zb, float* __restrict__ sq, int n) {
  int wid = blockIdx.x * 4 + (threadIdx.x >> 6);
  int lane = threadIdx.x & 63;
  if (wid >= n) return;
  float di = dinv[wid];
  float selfw = di * di;
  float acc = b2[lane] + h2[(size_t)wid * D_OUT + lane] * selfw;
  int e0 = offs[wid], e1 = offs[wid + 1];
  for (int e = e0; e < e1; ++e) {
    int s = csr_src[e];
    float w = csr_norm[e];
    acc += h2[(size_t)s * D_OUT + lane] * w;
  }
  unsigned short rb = f2bf(acc);
  zb[(size_t)wid * D_OUT + lane] = rb;
  float back = bf2f(rb);
  float ss = back * back;
#pragma unroll
  for (int o = 32; o > 0; o >>= 1) ss += __shfl_xor(ss, o, 64);
  if (lane == 0) sq[wid] = ss;
}

// ---------------- MFMA decode: 128x128 tile, bf16 Z @ Z^T, K=64 ----------------
// mode 0: 1D UPPER-TRIANGLE grid (d2 symmetric -> half the blocks), per-block
// max(d2) via plain store (single-address atomicMax cost 260us in R5).
// mode 1: full 2D grid, out = 1 - sqrt(d2/m2).
__global__ __launch_bounds__(256, 1) void decode_mfma_k(
    const unsigned short* __restrict__ zb, const float* __restrict__ sq,
    float* __restrict__ out, float* __restrict__ blockmax,
    const int* __restrict__ gmax, int n, int mode) {
  __shared__ __align__(16) char ZiB[128 * 128];
  __shared__ __align__(16) char ZjB[128 * 128];
  __shared__ float sqi[128];
  __shared__ float sqj[128];
  __shared__ float wmax[4];
  int t = threadIdx.x;

  int bi, bj;
  if (mode == 0) {
    int b = blockIdx.x;                       // b = bj*(bj+1)/2 + bi, bi <= bj
    int tj = (int)((sqrtf(8.f * (float)b + 1.f) - 1.f) * 0.5f);
    while ((tj + 1) * (tj + 2) / 2 <= b) ++tj;
    while (tj * (tj + 1) / 2 > b) --tj;
    bj = tj;
    bi = b - tj * (tj + 1) / 2;
  } else {
    bi = blockIdx.y; bj = blockIdx.x;
  }
  int i0 = bi * 128, j0 = bj * 128;

#pragma unroll
  for (int it = 0; it < 4; ++it) {
    int c = t + it * 256;
    int row = c >> 3, s = c & 7;
    int dstb = row * 128 + ((s * 16) ^ ((row & 7) << 4));
    s16x8 vi = *(const s16x8*)&zb[(size_t)(i0 + row) * D_OUT + s * 8];
    *(s16x8*)&ZiB[dstb] = vi;
    s16x8 vj = *(const s16x8*)&zb[(size_t)(j0 + row) * D_OUT + s * 8];
    *(s16x8*)&ZjB[dstb] = vj;
  }
  if (t < 128) sqi[t] = (i0 + t < n) ? sq[i0 + t] : 0.f;
  else { int tt = t - 128; sqj[tt] = (j0 + tt < n) ? sq[j0 + tt] : 0.f; }
  __syncthreads();

  int lane = t & 63;
  int wid = t >> 6;
  int wr = (wid >> 1) * 64;
  int wc = (wid & 1) * 64;
  int lrow = lane & 15;
  int lgrp = lane >> 4;
  int swz = (lrow & 7) << 4;

  f32x4 acc[4][4] = {};
#pragma unroll
  for (int ks = 0; ks < 2; ++ks) {
    s16x8 a[4], b[4];
    int kb = (ks * 64) ^ (lgrp * 16) ^ swz;
#pragma unroll
    for (int q = 0; q < 4; ++q) {
      a[q] = *(const s16x8*)&ZiB[(wr + q * 16 + lrow) * 128 + kb];
      b[q] = *(const s16x8*)&ZjB[(wc + q * 16 + lrow) * 128 + kb];
    }
#pragma unroll
    for (int rt = 0; rt < 4; ++rt)
#pragma unroll
      for (int ct = 0; ct < 4; ++ct)
        acc[rt][ct] = __builtin_amdgcn_mfma_f32_16x16x32_bf16(a[rt], b[ct], acc[rt][ct], 0, 0, 0);
  }

  float sqa[4][4], sqb[4];
#pragma unroll
  for (int rt = 0; rt < 4; ++rt)
#pragma unroll
    for (int reg = 0; reg < 4; ++reg)
      sqa[rt][reg] = sqi[wr + rt * 16 + lgrp * 4 + reg];
#pragma unroll
  for (int ct = 0; ct < 4; ++ct) sqb[ct] = sqj[wc + ct * 16 + lrow];

  if (mode == 0) {
    float lmax = 0.f;
#pragma unroll
    for (int rt = 0; rt < 4; ++rt)
#pragma unroll
      for (int ct = 0; ct < 4; ++ct)
#pragma unroll
        for (int reg = 0; reg < 4; ++reg) {
          int i = i0 + wr + rt * 16 + lgrp * 4 + reg;
          int j = j0 + wc + ct * 16 + lrow;
          if (i < n && j < n) {   // exclude ghosts: d2_ghost = |z_valid|^2 > 0 (R3 bug)
            float d2 = sqa[rt][reg] + sqb[ct] - 2.f * acc[rt][ct][reg];
            lmax = fmaxf(lmax, d2);
          }
        }
#pragma unroll
    for (int o = 32; o > 0; o >>= 1) lmax = fmaxf(lmax, __shfl_xor(lmax, o, 64));
    if (lane == 0) wmax[wid] = lmax;
    __syncthreads();
    if (t == 0) {
      float m = fmaxf(fmaxf(wmax[0], wmax[1]), fmaxf(wmax[2], wmax[3]));
      blockmax[blockIdx.x] = m;  // disjoint store, no atomic
    }
  } else {
    float m2 = __int_as_float(*gmax);
    float inv = (m2 > 0.f) ? (1.f / m2) : 0.f;
#pragma unroll
    for (int rt = 0; rt < 4; ++rt)
#pragma unroll
      for (int reg = 0; reg < 4; ++reg) {
        int i = i0 + wr + rt * 16 + lgrp * 4 + reg;
        if (i >= n) continue;
        size_t rowbase = (size_t)i * n;
#pragma unroll
        for (int ct = 0; ct < 4; ++ct) {
          int j = j0 + wc + ct * 16 + lrow;
          if (j >= n) continue;
          float d2 = sqa[rt][reg] + sqb[ct] - 2.f * acc[rt][ct][reg];
          out[rowbase + j] = (d2 > 0.f) ? (1.f - sqrtf(d2 * inv)) : 1.f;
        }
      }
  }
}

// ---------------- reduce block maxes -> gmax (single block) ----------------
__global__ void reduce_k(const float* __restrict__ bm, int* __restrict__ gmax, int nb) {
  __shared__ float s[1024];
  int t = threadIdx.x;
  float m = 0.f;
  for (int i = t; i < nb; i += 1024) m = fmaxf(m, bm[i]);
  s[t] = m;
  __syncthreads();
  for (int o = 512; o > 0; o >>= 1) {
    if (t < o) s[t] = fmaxf(s[t], s[t + o]);
    __syncthreads();
  }
  if (t == 0) gmax[0] = __float_as_int(s[0]);
}

extern "C" void kernel_launch(void* const* d_in, const int* in_sizes, int n_in,
                              void* d_out, int out_size, void* d_ws, size_t ws_size,
                              hipStream_t stream) {
  const float* x  = (const float*)d_in[0];
  const int* eraw = (const int*)d_in[1];
  const float* W1 = (const float*)d_in[2];
  const float* b1 = (const float*)d_in[3];
  const float* W2 = (const float*)d_in[4];
  const float* b2 = (const float*)d_in[5];
  float* out = (float*)d_out;

  const int n = in_sizes[0] / D_IN;   // 10000
  const int E = in_sizes[1] / 2;      // 320000
  const int gt = (n + 127) / 128;     // 79
  const int n_pad = gt * 128;         // 10112
  const int nbU = gt * (gt + 1) / 2;  // 3160 upper-triangle blocks

  // workspace carve (256B aligned)
  char* p = (char*)d_ws;
  auto alloc = [&](size_t bytes) {
    void* r = (void*)p;
    p += (bytes + 255) & ~(size_t)255;
    return r;
  };
  int*   cnt      = (int*)alloc((size_t)n * 4);
  int*   offs     = (int*)alloc((size_t)(n + 1) * 4);
  int*   cursor   = (int*)alloc((size_t)n * 4);
  int*   esrc     = (int*)alloc((size_t)E * 4);
  int*   edst     = (int*)alloc((size_t)E * 4);
  int*   csr_src  = (int*)alloc((size_t)E * 4);
  float* csr_norm = (float*)alloc((size_t)E * 4);
  float* dinv     = (float*)alloc((size_t)n * 4);
  unsigned short* hb = (unsigned short*)alloc((size_t)n * D_H * 2);
  float* h1       = (float*)alloc((size_t)n * D_H * 4);
  float* h2       = (float*)alloc((size_t)n * D_OUT * 4);
  unsigned short* zbuf = (unsigned short*)alloc((size_t)n_pad * D_OUT * 2);
  float* sq       = (float*)alloc((size_t)n * 4);
  float* blockmax = (float*)alloc((size_t)nbU * 4);
  int*   gmax     = (int*)alloc(4);

  const int npadElems = (n_pad - n) * D_OUT;
  const int prepT = n + 1 + npadElems + E;
  prep_k<<<(prepT + 255) / 256, 256, 0, stream>>>(eraw, cnt, cursor, gmax, zbuf,
                                                  esrc, edst, n, npadElems, E);
  count_k<<<512, 256, 0, stream>>>(edst, cnt, E);
  scan_k<<<1, 1024, 0, stream>>>(cnt, offs, dinv, n);
  fill_k<<<512, 256, 0, stream>>>(esrc, edst, offs, cursor, dinv, csr_src, csr_norm, E);

  // layer 1: h(bf16) = x @ W1 ; h1 = relu(agg(h))
  gemm1_k<<<dim3((n + 63) / 64, D_H / 64), 256, 0, stream>>>(x, W1, hb, n, D_H, D_IN);
  agg1_k<<<(n + 3) / 4, 256, 0, stream>>>(hb, offs, csr_src, csr_norm, dinv, b1, h1, n);

  // layer 2: h2 = h1 @ W2 ; z(bf16), sq = agg(h2)
  gemm2_k<<<(n + 31) / 32, 256, 0, stream>>>(h1, W2, h2, n, D_OUT, D_H);
  agg2_k<<<(n + 3) / 4, 256, 0, stream>>>(h2, offs, csr_src, csr_norm, dinv, b2, zbuf, sq, n);

  // decode: pass 0 = upper-tri per-block max(d2), reduce, pass 1 = full write
  decode_mfma_k<<<nbU, 256, 0, stream>>>(zbuf, sq, out, blockmax, gmax, n, 0);
  reduce_k<<<1, 1024, 0, stream>>>(blockmax, gmax, nbU);
  decode_mfma_k<<<dim3(gt, gt), 256, 0, stream>>>(zbuf, sq, out, blockmax, gmax, n, 1);
}